// Round 1
// baseline (702.464 us; speedup 1.0000x reference)
//
#include <hip/hip_runtime.h>
#include <hip/hip_bf16.h>
#include <math.h>

#define D_SSM 512
#define D_STATE 16

// ---------------- lw = log(w + 1e-6) ----------------
__global__ void lw_kernel(const float* __restrict__ w, float* __restrict__ lw, int n) {
    int i = blockIdx.x * blockDim.x + threadIdx.x;
    if (i < n) lw[i] = logf(w[i] + 1e-6f);
}

// ---------------- fp32 tiled GEMM: out[r,c] = sum_k X[r,k]*W[c,k] + epilogue ----------------
// mode 0: out = z + bias[c] + lw[r]*wcol[c*wcol_stride]          (x = feat @ W_in.T, concat col fused)
// mode 1: out = softplus(z + bias[c]) * sigmoid(lw[r]*wcol[c] + bw[c])   (delta)
__global__ __launch_bounds__(256) void gemm_xwT(
    const float* __restrict__ X, int xstride,
    const float* __restrict__ W, int wstride,
    float* __restrict__ out,
    const float* __restrict__ bias,
    const float* __restrict__ lw,
    const float* __restrict__ wcol, int wcol_stride,
    const float* __restrict__ bw,
    int M, int mode)
{
    __shared__ __align__(16) float Xs[32][68];
    __shared__ __align__(16) float Ws[32][68];
    const int tid = threadIdx.x;
    const int row0 = blockIdx.y * 64;
    const int col0 = blockIdx.x * 64;
    const int lm = tid >> 3;          // 0..31
    const int lk = (tid & 7) << 2;    // 0,4,...,28
    const int tx = tid & 15, ty = tid >> 4;

    float acc[4][4] = {};

    for (int k0 = 0; k0 < 512; k0 += 32) {
        #pragma unroll
        for (int r = 0; r < 2; r++) {
            int m = lm + r * 32;
            int grow = row0 + m;
            float4 v = make_float4(0.f, 0.f, 0.f, 0.f);
            if (grow < M) v = *(const float4*)(X + (size_t)grow * xstride + k0 + lk);
            Xs[lk + 0][m] = v.x; Xs[lk + 1][m] = v.y;
            Xs[lk + 2][m] = v.z; Xs[lk + 3][m] = v.w;
            int c = col0 + m;  // always < 512
            const float* wp = W + (size_t)c * wstride + k0 + lk;  // wstride may be odd (513): scalar loads
            Ws[lk + 0][m] = wp[0]; Ws[lk + 1][m] = wp[1];
            Ws[lk + 2][m] = wp[2]; Ws[lk + 3][m] = wp[3];
        }
        __syncthreads();
        #pragma unroll
        for (int k = 0; k < 32; k++) {
            float4 xa = *(const float4*)&Xs[k][ty << 2];
            float4 wb = *(const float4*)&Ws[k][tx << 2];
            float xr[4] = {xa.x, xa.y, xa.z, xa.w};
            float wr[4] = {wb.x, wb.y, wb.z, wb.w};
            #pragma unroll
            for (int i = 0; i < 4; i++)
                #pragma unroll
                for (int j = 0; j < 4; j++)
                    acc[i][j] += xr[i] * wr[j];
        }
        __syncthreads();
    }

    #pragma unroll
    for (int i = 0; i < 4; i++) {
        int grow = row0 + (ty << 2) + i;
        if (grow >= M) continue;
        float lwr = lw[grow];
        #pragma unroll
        for (int j = 0; j < 4; j++) {
            int c = col0 + (tx << 2) + j;
            float z = acc[i][j] + bias[c];
            float o;
            if (mode == 0) {
                o = z + lwr * wcol[(size_t)c * wcol_stride];
            } else {
                float sp = (z > 15.f) ? z : log1pf(__expf(z));
                float sg = 1.f / (1.f + __expf(-(lwr * wcol[c] + bw[c])));
                o = sp * sg;
            }
            out[(size_t)grow * D_SSM + c] = o;
        }
    }
}

// ---------------- B/C projections: Bm[n,s] = sum_d W_B[s,d]*x[n,d] + b_B[s] ----------------
__global__ __launch_bounds__(256) void bc_kernel(
    const float* __restrict__ x,
    const float* __restrict__ W_B, const float* __restrict__ b_B,
    const float* __restrict__ W_C, const float* __restrict__ b_C,
    float* __restrict__ Bm, float* __restrict__ Cm, int Nn)
{
    __shared__ float xs[512];
    const int n = blockIdx.x;
    const int t = threadIdx.x;
    xs[t] = x[(size_t)n * 512 + t];
    xs[t + 256] = x[(size_t)n * 512 + t + 256];
    __syncthreads();
    const int oid = t >> 3;     // 0..31  (0..15 -> B, 16..31 -> C)
    const int part = t & 7;
    const float* Wrow = (oid < 16) ? (W_B + (size_t)oid * 512) : (W_C + (size_t)(oid - 16) * 512);
    float sum = 0.f;
    for (int i = part; i < 512; i += 8) sum += Wrow[i] * xs[i];
    sum += __shfl_xor(sum, 1);
    sum += __shfl_xor(sum, 2);
    sum += __shfl_xor(sum, 4);
    if (part == 0) {
        if (oid < 16) Bm[(size_t)n * 16 + oid] = sum + b_B[oid];
        else          Cm[(size_t)n * 16 + (oid - 16)] = sum + b_C[oid - 16];
    }
}

// ---------------- tree scan (ancestor walk) + readout + LayerNorm ----------------
// H[n,d,s] = sum_{a on path root..n} delta[a,d]*x[a,d]*B[a,s] * exp(A[d,s]*(cumdelta below a))
__global__ __launch_bounds__(256) void scan_kernel(
    const float* __restrict__ x, const float* __restrict__ delta,
    const float* __restrict__ Bm, const float* __restrict__ Cm,
    const int* __restrict__ parent,
    const float* __restrict__ A_log, const float* __restrict__ Dv,
    const float* __restrict__ gamma, const float* __restrict__ beta,
    float* __restrict__ out, int Nn)
{
    const int n = blockIdx.x;
    const int t = threadIdx.x;
    const int d0 = t, d1 = t + 256;

    float As0[16], As1[16], acc0[16], acc1[16];
    #pragma unroll
    for (int s = 0; s < 16; s++) {
        As0[s] = -__expf(A_log[d0 * 16 + s]);
        As1[s] = -__expf(A_log[d1 * 16 + s]);
        acc0[s] = 0.f; acc1[s] = 0.f;
    }

    float cum0 = 0.f, cum1 = 0.f;
    int a = n;
    while (a >= 0) {
        float da0 = delta[(size_t)a * 512 + d0];
        float da1 = delta[(size_t)a * 512 + d1];
        float xa0 = x[(size_t)a * 512 + d0];
        float xa1 = x[(size_t)a * 512 + d1];
        float bx0 = da0 * xa0, bx1 = da1 * xa1;
        #pragma unroll
        for (int s = 0; s < 16; s++) {
            float Bs = Bm[a * 16 + s];
            acc0[s] += bx0 * Bs * __expf(As0[s] * cum0);
            acc1[s] += bx1 * Bs * __expf(As1[s] * cum1);
        }
        cum0 += da0; cum1 += da1;
        a = parent[a];
    }

    float xn0 = x[(size_t)n * 512 + d0], xn1 = x[(size_t)n * 512 + d1];
    float y0 = Dv[d0] * xn0, y1 = Dv[d1] * xn1;
    #pragma unroll
    for (int s = 0; s < 16; s++) {
        float Cs = Cm[(size_t)n * 16 + s];
        y0 += Cs * acc0[s];
        y1 += Cs * acc1[s];
    }

    // block LayerNorm over 512 channels
    float s1 = y0 + y1;
    float s2 = y0 * y0 + y1 * y1;
    #pragma unroll
    for (int off = 32; off > 0; off >>= 1) {
        s1 += __shfl_xor(s1, off);
        s2 += __shfl_xor(s2, off);
    }
    __shared__ float red[8];
    int wid = t >> 6, lane = t & 63;
    if (lane == 0) { red[wid] = s1; red[wid + 4] = s2; }
    __syncthreads();
    float S1 = red[0] + red[1] + red[2] + red[3];
    float S2 = red[4] + red[5] + red[6] + red[7];
    float mu = S1 * (1.f / 512.f);
    float var = S2 * (1.f / 512.f) - mu * mu;
    float inv = rsqrtf(var + 1e-5f);
    out[(size_t)n * 512 + d0] = (y0 - mu) * inv * gamma[d0] + beta[d0];
    out[(size_t)n * 512 + d1] = (y1 - mu) * inv * gamma[d1] + beta[d1];
}

extern "C" void kernel_launch(void* const* d_in, const int* in_sizes, int n_in,
                              void* d_out, int out_size, void* d_ws, size_t ws_size,
                              hipStream_t stream) {
    const float* s_in   = (const float*)d_in[0];
    const float* w      = (const float*)d_in[1];
    const int*   parent = (const int*)d_in[2];
    // d_in[3] = depth (unused: walk terminates at parent < 0)
    const float* W_in    = (const float*)d_in[4];
    const float* b_in    = (const float*)d_in[5];
    const float* W_delta = (const float*)d_in[6];
    const float* b_delta = (const float*)d_in[7];
    const float* W_w     = (const float*)d_in[8];
    const float* b_w     = (const float*)d_in[9];
    const float* A_log   = (const float*)d_in[10];
    const float* Dv      = (const float*)d_in[11];
    const float* W_B     = (const float*)d_in[12];
    const float* b_B     = (const float*)d_in[13];
    const float* W_C     = (const float*)d_in[14];
    const float* b_C     = (const float*)d_in[15];
    const float* gamma   = (const float*)d_in[16];
    const float* beta    = (const float*)d_in[17];
    float* out = (float*)d_out;

    const int Nn = in_sizes[1];           // 16383
    const int Mpad = 16384;

    float* ws    = (float*)d_ws;
    float* lw    = ws;                                // 16384
    float* x     = lw + Mpad;                         // 16384*512
    float* delta = x + (size_t)Mpad * 512;            // 16384*512
    float* Bm    = delta + (size_t)Mpad * 512;        // 16384*16
    float* Cm    = Bm + (size_t)Mpad * 16;            // 16384*16

    lw_kernel<<<(Nn + 255) / 256, 256, 0, stream>>>(w, lw, Nn);

    dim3 gg(512 / 64, Mpad / 64);  // (8, 256)
    // x = [s | lw] @ W_in.T + b_in   (concat column fused via wcol = W_in[:,512])
    gemm_xwT<<<gg, 256, 0, stream>>>(s_in, 512, W_in, 513, x,
                                     b_in, lw, W_in + 512, 513, nullptr, Nn, 0);
    // delta = softplus(x @ W_delta.T + b_delta) * sigmoid(lw*W_w + b_w)
    gemm_xwT<<<gg, 256, 0, stream>>>(x, 512, W_delta, 512, delta,
                                     b_delta, lw, W_w, 1, b_w, Nn, 1);

    bc_kernel<<<Nn, 256, 0, stream>>>(x, W_B, b_B, W_C, b_C, Bm, Cm, Nn);

    scan_kernel<<<Nn, 256, 0, stream>>>(x, delta, Bm, Cm, parent, A_log, Dv,
                                        gamma, beta, out, Nn);
}

// Round 2
// 619.035 us; speedup vs baseline: 1.1348x; 1.1348x over previous
//
#include <hip/hip_runtime.h>
#include <hip/hip_bf16.h>
#include <math.h>

#define D_SSM 512
#define D_STATE 16
#define CKPT_BASE 511     // first index of level 9
#define CKPT_END 1023     // first index of level 10
#define N_CKPT 512        // nodes at level 9

// ---------------- lw = log(w + 1e-6) ----------------
__global__ void lw_kernel(const float* __restrict__ w, float* __restrict__ lw, int n) {
    int i = blockIdx.x * blockDim.x + threadIdx.x;
    if (i < n) lw[i] = logf(w[i] + 1e-6f);
}

// ---------------- fp32 tiled GEMM: out[r,c] = sum_k X[r,k]*W[c,k] + epilogue ----------------
__global__ __launch_bounds__(256) void gemm_xwT(
    const float* __restrict__ X, int xstride,
    const float* __restrict__ W, int wstride,
    float* __restrict__ out,
    const float* __restrict__ bias,
    const float* __restrict__ lw,
    const float* __restrict__ wcol, int wcol_stride,
    const float* __restrict__ bw,
    int M, int mode)
{
    __shared__ __align__(16) float Xs[32][68];
    __shared__ __align__(16) float Ws[32][68];
    const int tid = threadIdx.x;
    const int row0 = blockIdx.y * 64;
    const int col0 = blockIdx.x * 64;
    const int lm = tid >> 3;
    const int lk = (tid & 7) << 2;
    const int tx = tid & 15, ty = tid >> 4;

    float acc[4][4] = {};

    for (int k0 = 0; k0 < 512; k0 += 32) {
        #pragma unroll
        for (int r = 0; r < 2; r++) {
            int m = lm + r * 32;
            int grow = row0 + m;
            float4 v = make_float4(0.f, 0.f, 0.f, 0.f);
            if (grow < M) v = *(const float4*)(X + (size_t)grow * xstride + k0 + lk);
            Xs[lk + 0][m] = v.x; Xs[lk + 1][m] = v.y;
            Xs[lk + 2][m] = v.z; Xs[lk + 3][m] = v.w;
            int c = col0 + m;
            const float* wp = W + (size_t)c * wstride + k0 + lk;
            Ws[lk + 0][m] = wp[0]; Ws[lk + 1][m] = wp[1];
            Ws[lk + 2][m] = wp[2]; Ws[lk + 3][m] = wp[3];
        }
        __syncthreads();
        #pragma unroll
        for (int k = 0; k < 32; k++) {
            float4 xa = *(const float4*)&Xs[k][ty << 2];
            float4 wb = *(const float4*)&Ws[k][tx << 2];
            float xr[4] = {xa.x, xa.y, xa.z, xa.w};
            float wr[4] = {wb.x, wb.y, wb.z, wb.w};
            #pragma unroll
            for (int i = 0; i < 4; i++)
                #pragma unroll
                for (int j = 0; j < 4; j++)
                    acc[i][j] += xr[i] * wr[j];
        }
        __syncthreads();
    }

    #pragma unroll
    for (int i = 0; i < 4; i++) {
        int grow = row0 + (ty << 2) + i;
        if (grow >= M) continue;
        float lwr = lw[grow];
        #pragma unroll
        for (int j = 0; j < 4; j++) {
            int c = col0 + (tx << 2) + j;
            float z = acc[i][j] + bias[c];
            float o;
            if (mode == 0) {
                o = z + lwr * wcol[(size_t)c * wcol_stride];
            } else {
                float sp = (z > 15.f) ? z : log1pf(__expf(z));
                float sg = 1.f / (1.f + __expf(-(lwr * wcol[c] + bw[c])));
                o = sp * sg;
            }
            out[(size_t)grow * D_SSM + c] = o;
        }
    }
}

// ---------------- B/C projections ----------------
__global__ __launch_bounds__(256) void bc_kernel(
    const float* __restrict__ x,
    const float* __restrict__ W_B, const float* __restrict__ b_B,
    const float* __restrict__ W_C, const float* __restrict__ b_C,
    float* __restrict__ Bm, float* __restrict__ Cm, int Nn)
{
    __shared__ float xs[512];
    const int n = blockIdx.x;
    const int t = threadIdx.x;
    xs[t] = x[(size_t)n * 512 + t];
    xs[t + 256] = x[(size_t)n * 512 + t + 256];
    __syncthreads();
    const int oid = t >> 3;
    const int part = t & 7;
    const float* Wrow = (oid < 16) ? (W_B + (size_t)oid * 512) : (W_C + (size_t)(oid - 16) * 512);
    float sum = 0.f;
    for (int i = part; i < 512; i += 8) sum += Wrow[i] * xs[i];
    sum += __shfl_xor(sum, 1);
    sum += __shfl_xor(sum, 2);
    sum += __shfl_xor(sum, 4);
    if (part == 0) {
        if (oid < 16) Bm[(size_t)n * 16 + oid] = sum + b_B[oid];
        else          Cm[(size_t)n * 16 + (oid - 16)] = sum + b_C[oid - 16];
    }
}

// ---- shared walk-step device helpers ----
// fast path valid when As[s] == (s+1)*As[0] (A_log is log(arange(1..17)) broadcast)
__device__ __forceinline__ bool geo_check(const float* As) {
    bool ok = true;
    #pragma unroll
    for (int s = 1; s < 16; s++) {
        float want = (float)(s + 1) * As[0];
        ok = ok && (fabsf(As[s] - want) <= 1e-4f * (float)(s + 1));
    }
    return ok;
}

// ---------------- checkpoint kernel: H for all level-9 nodes ----------------
__global__ __launch_bounds__(256) void ckpt_kernel(
    const float* __restrict__ x, const float* __restrict__ delta,
    const float* __restrict__ Bm, const float* __restrict__ A_log,
    float* __restrict__ H9)
{
    const int n9 = blockIdx.x;            // 0..511
    const int t = threadIdx.x;
    const int d0 = t, d1 = t + 256;

    float As0[16], As1[16], acc0[16], acc1[16];
    #pragma unroll
    for (int s = 0; s < 16; s++) {
        As0[s] = -__expf(A_log[d0 * 16 + s]);
        As1[s] = -__expf(A_log[d1 * 16 + s]);
        acc0[s] = 0.f; acc1[s] = 0.f;
    }
    const bool fast = geo_check(As0) && geo_check(As1);

    float cum0 = 0.f, cum1 = 0.f;
    int a = CKPT_BASE + n9;
    while (a >= 0) {
        float da0 = delta[(size_t)a * 512 + d0];
        float da1 = delta[(size_t)a * 512 + d1];
        float bx0 = da0 * x[(size_t)a * 512 + d0];
        float bx1 = da1 * x[(size_t)a * 512 + d1];
        if (fast) {
            float r0 = __expf(As0[0] * cum0);
            float r1 = __expf(As1[0] * cum1);
            float pw0 = r0, pw1 = r1;
            #pragma unroll
            for (int s = 0; s < 16; s++) {
                float Bs = Bm[a * 16 + s];
                acc0[s] = fmaf(bx0 * pw0, Bs, acc0[s]);
                acc1[s] = fmaf(bx1 * pw1, Bs, acc1[s]);
                pw0 *= r0; pw1 *= r1;
            }
        } else {
            #pragma unroll
            for (int s = 0; s < 16; s++) {
                float Bs = Bm[a * 16 + s];
                acc0[s] = fmaf(bx0 * __expf(As0[s] * cum0), Bs, acc0[s]);
                acc1[s] = fmaf(bx1 * __expf(As1[s] * cum1), Bs, acc1[s]);
            }
        }
        cum0 += da0; cum1 += da1;
        a = (a - 1) >> 1;   // root 0 -> -1
    }

    float* p0 = H9 + ((size_t)n9 * 512 + d0) * 16;
    float* p1 = H9 + ((size_t)n9 * 512 + d1) * 16;
    #pragma unroll
    for (int s = 0; s < 16; s++) { p0[s] = acc0[s]; p1[s] = acc1[s]; }
}

// ---------------- scan + readout + LayerNorm (checkpoint-accelerated) ----------------
__global__ __launch_bounds__(256) void scan_kernel(
    const float* __restrict__ x, const float* __restrict__ delta,
    const float* __restrict__ Bm, const float* __restrict__ Cm,
    const float* __restrict__ H9,
    const float* __restrict__ A_log, const float* __restrict__ Dv,
    const float* __restrict__ gamma, const float* __restrict__ beta,
    float* __restrict__ out, int Nn)
{
    const int n = blockIdx.x;
    const int t = threadIdx.x;
    const int d0 = t, d1 = t + 256;

    float As0[16], As1[16], acc0[16], acc1[16];
    #pragma unroll
    for (int s = 0; s < 16; s++) {
        As0[s] = -__expf(A_log[d0 * 16 + s]);
        As1[s] = -__expf(A_log[d1 * 16 + s]);
        acc0[s] = 0.f; acc1[s] = 0.f;
    }
    const bool fast = geo_check(As0) && geo_check(As1);

    float cum0 = 0.f, cum1 = 0.f;
    int a = n;
    // walk levels >= 10
    while (a >= CKPT_END) {
        float da0 = delta[(size_t)a * 512 + d0];
        float da1 = delta[(size_t)a * 512 + d1];
        float bx0 = da0 * x[(size_t)a * 512 + d0];
        float bx1 = da1 * x[(size_t)a * 512 + d1];
        if (fast) {
            float r0 = __expf(As0[0] * cum0);
            float r1 = __expf(As1[0] * cum1);
            float pw0 = r0, pw1 = r1;
            #pragma unroll
            for (int s = 0; s < 16; s++) {
                float Bs = Bm[a * 16 + s];
                acc0[s] = fmaf(bx0 * pw0, Bs, acc0[s]);
                acc1[s] = fmaf(bx1 * pw1, Bs, acc1[s]);
                pw0 *= r0; pw1 *= r1;
            }
        } else {
            #pragma unroll
            for (int s = 0; s < 16; s++) {
                float Bs = Bm[a * 16 + s];
                acc0[s] = fmaf(bx0 * __expf(As0[s] * cum0), Bs, acc0[s]);
                acc1[s] = fmaf(bx1 * __expf(As1[s] * cum1), Bs, acc1[s]);
            }
        }
        cum0 += da0; cum1 += da1;
        a = (a - 1) >> 1;
    }

    if (n >= CKPT_END) {
        // splice in checkpointed state of the level-9 ancestor `a`
        const float* p0 = H9 + ((size_t)(a - CKPT_BASE) * 512 + d0) * 16;
        const float* p1 = H9 + ((size_t)(a - CKPT_BASE) * 512 + d1) * 16;
        if (fast) {
            float r0 = __expf(As0[0] * cum0);
            float r1 = __expf(As1[0] * cum1);
            float pw0 = r0, pw1 = r1;
            #pragma unroll
            for (int s = 0; s < 16; s++) {
                acc0[s] = fmaf(pw0, p0[s], acc0[s]);
                acc1[s] = fmaf(pw1, p1[s], acc1[s]);
                pw0 *= r0; pw1 *= r1;
            }
        } else {
            #pragma unroll
            for (int s = 0; s < 16; s++) {
                acc0[s] = fmaf(__expf(As0[s] * cum0), p0[s], acc0[s]);
                acc1[s] = fmaf(__expf(As1[s] * cum1), p1[s], acc1[s]);
            }
        }
    } else {
        // shallow node (levels 0..9): finish the walk to the root
        while (a >= 0) {
            float da0 = delta[(size_t)a * 512 + d0];
            float da1 = delta[(size_t)a * 512 + d1];
            float bx0 = da0 * x[(size_t)a * 512 + d0];
            float bx1 = da1 * x[(size_t)a * 512 + d1];
            if (fast) {
                float r0 = __expf(As0[0] * cum0);
                float r1 = __expf(As1[0] * cum1);
                float pw0 = r0, pw1 = r1;
                #pragma unroll
                for (int s = 0; s < 16; s++) {
                    float Bs = Bm[a * 16 + s];
                    acc0[s] = fmaf(bx0 * pw0, Bs, acc0[s]);
                    acc1[s] = fmaf(bx1 * pw1, Bs, acc1[s]);
                    pw0 *= r0; pw1 *= r1;
                }
            } else {
                #pragma unroll
                for (int s = 0; s < 16; s++) {
                    float Bs = Bm[a * 16 + s];
                    acc0[s] = fmaf(bx0 * __expf(As0[s] * cum0), Bs, acc0[s]);
                    acc1[s] = fmaf(bx1 * __expf(As1[s] * cum1), Bs, acc1[s]);
                }
            }
            cum0 += da0; cum1 += da1;
            a = (a - 1) >> 1;
        }
    }

    float xn0 = x[(size_t)n * 512 + d0], xn1 = x[(size_t)n * 512 + d1];
    float y0 = Dv[d0] * xn0, y1 = Dv[d1] * xn1;
    #pragma unroll
    for (int s = 0; s < 16; s++) {
        float Cs = Cm[(size_t)n * 16 + s];
        y0 += Cs * acc0[s];
        y1 += Cs * acc1[s];
    }

    // block LayerNorm over 512 channels
    float s1 = y0 + y1;
    float s2 = y0 * y0 + y1 * y1;
    #pragma unroll
    for (int off = 32; off > 0; off >>= 1) {
        s1 += __shfl_xor(s1, off);
        s2 += __shfl_xor(s2, off);
    }
    __shared__ float red[8];
    int wid = t >> 6, lane = t & 63;
    if (lane == 0) { red[wid] = s1; red[wid + 4] = s2; }
    __syncthreads();
    float S1 = red[0] + red[1] + red[2] + red[3];
    float S2 = red[4] + red[5] + red[6] + red[7];
    float mu = S1 * (1.f / 512.f);
    float var = S2 * (1.f / 512.f) - mu * mu;
    float inv = rsqrtf(var + 1e-5f);
    out[(size_t)n * 512 + d0] = (y0 - mu) * inv * gamma[d0] + beta[d0];
    out[(size_t)n * 512 + d1] = (y1 - mu) * inv * gamma[d1] + beta[d1];
}

extern "C" void kernel_launch(void* const* d_in, const int* in_sizes, int n_in,
                              void* d_out, int out_size, void* d_ws, size_t ws_size,
                              hipStream_t stream) {
    const float* s_in   = (const float*)d_in[0];
    const float* w      = (const float*)d_in[1];
    const float* W_in    = (const float*)d_in[4];
    const float* b_in    = (const float*)d_in[5];
    const float* W_delta = (const float*)d_in[6];
    const float* b_delta = (const float*)d_in[7];
    const float* W_w     = (const float*)d_in[8];
    const float* b_w     = (const float*)d_in[9];
    const float* A_log   = (const float*)d_in[10];
    const float* Dv      = (const float*)d_in[11];
    const float* W_B     = (const float*)d_in[12];
    const float* b_B     = (const float*)d_in[13];
    const float* W_C     = (const float*)d_in[14];
    const float* b_C     = (const float*)d_in[15];
    const float* gamma   = (const float*)d_in[16];
    const float* beta    = (const float*)d_in[17];
    float* out = (float*)d_out;

    const int Nn = in_sizes[1];           // 16383
    const int Mpad = 16384;

    float* ws    = (float*)d_ws;
    float* lw    = ws;                                // 16384
    float* x     = lw + Mpad;                         // 16384*512
    float* delta = x + (size_t)Mpad * 512;            // 16384*512
    float* Bm    = delta + (size_t)Mpad * 512;        // 16384*16
    float* Cm    = Bm + (size_t)Mpad * 16;            // 16384*16
    float* H9    = Cm + (size_t)Mpad * 16;            // 512*512*16 = 16.8 MB

    lw_kernel<<<(Nn + 255) / 256, 256, 0, stream>>>(w, lw, Nn);

    dim3 gg(512 / 64, Mpad / 64);
    gemm_xwT<<<gg, 256, 0, stream>>>(s_in, 512, W_in, 513, x,
                                     b_in, lw, W_in + 512, 513, nullptr, Nn, 0);
    gemm_xwT<<<gg, 256, 0, stream>>>(x, 512, W_delta, 512, delta,
                                     b_delta, lw, W_w, 1, b_w, Nn, 1);

    bc_kernel<<<Nn, 256, 0, stream>>>(x, W_B, b_B, W_C, b_C, Bm, Cm, Nn);

    ckpt_kernel<<<N_CKPT, 256, 0, stream>>>(x, delta, Bm, A_log, H9);

    scan_kernel<<<Nn, 256, 0, stream>>>(x, delta, Bm, Cm, H9, A_log, Dv,
                                        gamma, beta, out, Nn);
}

// Round 3
// 441.513 us; speedup vs baseline: 1.5910x; 1.4021x over previous
//
#include <hip/hip_runtime.h>
#include <hip/hip_bf16.h>
#include <math.h>

#define D_SSM 512
#define D_STATE 16
#define CKPT_BASE 511     // first index of level 9
#define CKPT_END 1023     // first index of level 10
#define N_CKPT 512        // nodes at level 9
#define MPAD 16384

typedef __attribute__((ext_vector_type(8))) short short8;
typedef __attribute__((ext_vector_type(4))) float floatx4;

__device__ __forceinline__ unsigned short f2bf(float f) {
    unsigned int u = __float_as_uint(f);
    unsigned int r = (u + 0x7fffu + ((u >> 16) & 1u)) >> 16;
    return (unsigned short)r;
}
__device__ __forceinline__ float bf2f(unsigned short u) {
    return __uint_as_float(((unsigned int)u) << 16);
}
__device__ __forceinline__ void g2lds16(const void* g, void* l) {
    __builtin_amdgcn_global_load_lds(
        (const __attribute__((address_space(1))) void*)g,
        (__attribute__((address_space(3))) void*)l, 16, 0, 0);
}

// ---------------- prep: cast s/W_in/W_delta to bf16, compute lw ----------------
__global__ __launch_bounds__(256) void prep_kernel(
    const float* __restrict__ s, const float* __restrict__ w,
    const float* __restrict__ W_in, const float* __restrict__ W_delta,
    unsigned short* __restrict__ s_bf, float* __restrict__ lw,
    unsigned short* __restrict__ Win_bf, unsigned short* __restrict__ Wd_bf, int Nn)
{
    const int b = blockIdx.x, t = threadIdx.x;
    if (b < MPAD) {
        unsigned int pack = 0;
        if (b < Nn) {
            float2 sv = *(const float2*)(s + (size_t)b * 512 + t * 2);
            pack = (unsigned int)f2bf(sv.x) | ((unsigned int)f2bf(sv.y) << 16);
        }
        *(unsigned int*)(s_bf + (size_t)b * 512 + t * 2) = pack;
        if (t == 0) lw[b] = (b < Nn) ? logf(w[b] + 1e-6f) : 0.f;
    } else if (b < MPAD + 512) {
        int c = b - MPAD;
        float a0 = W_in[(size_t)c * 513 + t * 2];
        float a1 = W_in[(size_t)c * 513 + t * 2 + 1];
        *(unsigned int*)(Win_bf + (size_t)c * 512 + t * 2) =
            (unsigned int)f2bf(a0) | ((unsigned int)f2bf(a1) << 16);
    } else {
        int c = b - MPAD - 512;
        float2 wv = *(const float2*)(W_delta + (size_t)c * 512 + t * 2);
        *(unsigned int*)(Wd_bf + (size_t)c * 512 + t * 2) =
            (unsigned int)f2bf(wv.x) | ((unsigned int)f2bf(wv.y) << 16);
    }
}

// ---------------- bf16 MFMA GEMM: out[r,c] = sum_k A[r,k]*W[c,k] + epilogue ----------------
// mode 0: o = z + bias[c] + lw[r]*wcol[c*wcol_stride]; store bf16 -> outbf
// mode 1: o = softplus(z+bias[c]) * sigmoid(lw[r]*wcol[c]+bw[c]); store fp32 -> outf
__global__ __launch_bounds__(256) void gemm_mfma(
    const unsigned short* __restrict__ Abf,   // [16384][512] bf16
    const unsigned short* __restrict__ Wbf,   // [512][512] bf16 (row-major, K-contig)
    float* __restrict__ outf,
    unsigned short* __restrict__ outbf,
    const float* __restrict__ bias,
    const float* __restrict__ lw,
    const float* __restrict__ wcol, int wcol_stride,
    const float* __restrict__ bw,
    int mode)
{
    __shared__ __align__(16) short As[128 * 32];
    __shared__ __align__(16) short Bs[128 * 32];
    const int tid = threadIdx.x;
    const int wave = tid >> 6, lane = tid & 63;
    const int row0 = blockIdx.y * 128;
    const int col0 = blockIdx.x * 128;
    const int wr = (wave >> 1) * 64;     // wave row offset in tile
    const int wc = (wave & 1) * 64;      // wave col offset

    floatx4 acc[4][4] = {};

    const int srow = lane >> 2;          // 0..15 within 16-row chunk
    const int scol = (lane & 3) * 8;     // bf16 element col

    for (int k0 = 0; k0 < 512; k0 += 32) {
        #pragma unroll
        for (int j = 0; j < 2; j++) {
            int c = wave * 2 + j;            // chunk 0..7 -> rows c*16..c*16+15
            int r = c * 16 + srow;
            g2lds16(Abf + (size_t)(row0 + r) * 512 + k0 + scol, (char*)As + c * 1024);
            g2lds16(Wbf + (size_t)(col0 + r) * 512 + k0 + scol, (char*)Bs + c * 1024);
        }
        __syncthreads();

        short8 af[4], bfr[4];
        #pragma unroll
        for (int i = 0; i < 4; i++) {
            int m = wr + i * 16 + (lane & 15);
            af[i] = *(const short8*)&As[m * 32 + (lane >> 4) * 8];
            int n = wc + i * 16 + (lane & 15);
            bfr[i] = *(const short8*)&Bs[n * 32 + (lane >> 4) * 8];
        }
        #pragma unroll
        for (int i = 0; i < 4; i++)
            #pragma unroll
            for (int j2 = 0; j2 < 4; j2++)
                acc[i][j2] = __builtin_amdgcn_mfma_f32_16x16x32_bf16(af[i], bfr[j2], acc[i][j2], 0, 0, 0);
        __syncthreads();
    }

    // epilogue: C/D layout col=lane&15, row=(lane>>4)*4+reg
    #pragma unroll
    for (int i = 0; i < 4; i++) {
        #pragma unroll
        for (int reg = 0; reg < 4; reg++) {
            int r = row0 + wr + i * 16 + (lane >> 4) * 4 + reg;
            float lwr = lw[r];
            #pragma unroll
            for (int j = 0; j < 4; j++) {
                int c = col0 + wc + j * 16 + (lane & 15);
                float z = acc[i][j][reg] + bias[c];
                if (mode == 0) {
                    float o = z + lwr * wcol[(size_t)c * wcol_stride];
                    outbf[(size_t)r * 512 + c] = f2bf(o);
                } else {
                    float sp = (z > 15.f) ? z : log1pf(__expf(z));
                    float sg = 1.f / (1.f + __expf(-(lwr * wcol[c] + bw[c])));
                    outf[(size_t)r * 512 + c] = sp * sg;
                }
            }
        }
    }
}

// ---------------- B/C projections (x in bf16) ----------------
__global__ __launch_bounds__(256) void bc_kernel(
    const unsigned short* __restrict__ x_bf,
    const float* __restrict__ W_B, const float* __restrict__ b_B,
    const float* __restrict__ W_C, const float* __restrict__ b_C,
    float* __restrict__ Bm, float* __restrict__ Cm, int Nn)
{
    __shared__ float xs[512];
    const int n = blockIdx.x;
    const int t = threadIdx.x;
    xs[t] = bf2f(x_bf[(size_t)n * 512 + t]);
    xs[t + 256] = bf2f(x_bf[(size_t)n * 512 + t + 256]);
    __syncthreads();
    const int oid = t >> 3;
    const int part = t & 7;
    const float* Wrow = (oid < 16) ? (W_B + (size_t)oid * 512) : (W_C + (size_t)(oid - 16) * 512);
    float sum = 0.f;
    for (int i = part; i < 512; i += 8) sum += Wrow[i] * xs[i];
    sum += __shfl_xor(sum, 1);
    sum += __shfl_xor(sum, 2);
    sum += __shfl_xor(sum, 4);
    if (part == 0) {
        if (oid < 16) Bm[(size_t)n * 16 + oid] = sum + b_B[oid];
        else          Cm[(size_t)n * 16 + (oid - 16)] = sum + b_C[oid - 16];
    }
}

// fast path valid when As[s] == (s+1)*As[0]
__device__ __forceinline__ bool geo_check(const float* As) {
    bool ok = true;
    #pragma unroll
    for (int s = 1; s < 16; s++) {
        float want = (float)(s + 1) * As[0];
        ok = ok && (fabsf(As[s] - want) <= 1e-4f * (float)(s + 1));
    }
    return ok;
}

// ---------------- checkpoint kernel: H for all level-9 nodes ----------------
__global__ __launch_bounds__(256) void ckpt_kernel(
    const unsigned short* __restrict__ x_bf, const float* __restrict__ delta,
    const float* __restrict__ Bm, const float* __restrict__ A_log,
    float* __restrict__ H9)
{
    const int n9 = blockIdx.x;
    const int t = threadIdx.x;
    const int d0 = t, d1 = t + 256;

    float As0[16], As1[16], acc0[16], acc1[16];
    #pragma unroll
    for (int s = 0; s < 16; s++) {
        As0[s] = -__expf(A_log[d0 * 16 + s]);
        As1[s] = -__expf(A_log[d1 * 16 + s]);
        acc0[s] = 0.f; acc1[s] = 0.f;
    }
    const bool fast = geo_check(As0) && geo_check(As1);

    float cum0 = 0.f, cum1 = 0.f;
    int a = CKPT_BASE + n9;
    while (a >= 0) {
        float da0 = delta[(size_t)a * 512 + d0];
        float da1 = delta[(size_t)a * 512 + d1];
        float bx0 = da0 * bf2f(x_bf[(size_t)a * 512 + d0]);
        float bx1 = da1 * bf2f(x_bf[(size_t)a * 512 + d1]);
        if (fast) {
            float r0 = __expf(As0[0] * cum0);
            float r1 = __expf(As1[0] * cum1);
            float pw0 = r0, pw1 = r1;
            #pragma unroll
            for (int s = 0; s < 16; s++) {
                float Bs = Bm[a * 16 + s];
                acc0[s] = fmaf(bx0 * pw0, Bs, acc0[s]);
                acc1[s] = fmaf(bx1 * pw1, Bs, acc1[s]);
                pw0 *= r0; pw1 *= r1;
            }
        } else {
            #pragma unroll
            for (int s = 0; s < 16; s++) {
                float Bs = Bm[a * 16 + s];
                acc0[s] = fmaf(bx0 * __expf(As0[s] * cum0), Bs, acc0[s]);
                acc1[s] = fmaf(bx1 * __expf(As1[s] * cum1), Bs, acc1[s]);
            }
        }
        cum0 += da0; cum1 += da1;
        a = (a - 1) >> 1;
    }

    float* p0 = H9 + ((size_t)n9 * 512 + d0) * 16;
    float* p1 = H9 + ((size_t)n9 * 512 + d1) * 16;
    #pragma unroll
    for (int s = 0; s < 16; s++) { p0[s] = acc0[s]; p1[s] = acc1[s]; }
}

// ---------------- scan + readout + LayerNorm ----------------
__global__ __launch_bounds__(256) void scan_kernel(
    const unsigned short* __restrict__ x_bf, const float* __restrict__ delta,
    const float* __restrict__ Bm, const float* __restrict__ Cm,
    const float* __restrict__ H9,
    const float* __restrict__ A_log, const float* __restrict__ Dv,
    const float* __restrict__ gamma, const float* __restrict__ beta,
    float* __restrict__ out, int Nn)
{
    const int n = blockIdx.x;
    const int t = threadIdx.x;
    const int d0 = t, d1 = t + 256;

    float As0[16], As1[16], acc0[16], acc1[16];
    #pragma unroll
    for (int s = 0; s < 16; s++) {
        As0[s] = -__expf(A_log[d0 * 16 + s]);
        As1[s] = -__expf(A_log[d1 * 16 + s]);
        acc0[s] = 0.f; acc1[s] = 0.f;
    }
    const bool fast = geo_check(As0) && geo_check(As1);

    float cum0 = 0.f, cum1 = 0.f;
    int a = n;
    while (a >= CKPT_END) {
        float da0 = delta[(size_t)a * 512 + d0];
        float da1 = delta[(size_t)a * 512 + d1];
        float bx0 = da0 * bf2f(x_bf[(size_t)a * 512 + d0]);
        float bx1 = da1 * bf2f(x_bf[(size_t)a * 512 + d1]);
        if (fast) {
            float r0 = __expf(As0[0] * cum0);
            float r1 = __expf(As1[0] * cum1);
            float pw0 = r0, pw1 = r1;
            #pragma unroll
            for (int s = 0; s < 16; s++) {
                float Bs = Bm[a * 16 + s];
                acc0[s] = fmaf(bx0 * pw0, Bs, acc0[s]);
                acc1[s] = fmaf(bx1 * pw1, Bs, acc1[s]);
                pw0 *= r0; pw1 *= r1;
            }
        } else {
            #pragma unroll
            for (int s = 0; s < 16; s++) {
                float Bs = Bm[a * 16 + s];
                acc0[s] = fmaf(bx0 * __expf(As0[s] * cum0), Bs, acc0[s]);
                acc1[s] = fmaf(bx1 * __expf(As1[s] * cum1), Bs, acc1[s]);
            }
        }
        cum0 += da0; cum1 += da1;
        a = (a - 1) >> 1;
    }

    if (n >= CKPT_END) {
        const float* p0 = H9 + ((size_t)(a - CKPT_BASE) * 512 + d0) * 16;
        const float* p1 = H9 + ((size_t)(a - CKPT_BASE) * 512 + d1) * 16;
        if (fast) {
            float r0 = __expf(As0[0] * cum0);
            float r1 = __expf(As1[0] * cum1);
            float pw0 = r0, pw1 = r1;
            #pragma unroll
            for (int s = 0; s < 16; s++) {
                acc0[s] = fmaf(pw0, p0[s], acc0[s]);
                acc1[s] = fmaf(pw1, p1[s], acc1[s]);
                pw0 *= r0; pw1 *= r1;
            }
        } else {
            #pragma unroll
            for (int s = 0; s < 16; s++) {
                acc0[s] = fmaf(__expf(As0[s] * cum0), p0[s], acc0[s]);
                acc1[s] = fmaf(__expf(As1[s] * cum1), p1[s], acc1[s]);
            }
        }
    } else {
        while (a >= 0) {
            float da0 = delta[(size_t)a * 512 + d0];
            float da1 = delta[(size_t)a * 512 + d1];
            float bx0 = da0 * bf2f(x_bf[(size_t)a * 512 + d0]);
            float bx1 = da1 * bf2f(x_bf[(size_t)a * 512 + d1]);
            if (fast) {
                float r0 = __expf(As0[0] * cum0);
                float r1 = __expf(As1[0] * cum1);
                float pw0 = r0, pw1 = r1;
                #pragma unroll
                for (int s = 0; s < 16; s++) {
                    float Bs = Bm[a * 16 + s];
                    acc0[s] = fmaf(bx0 * pw0, Bs, acc0[s]);
                    acc1[s] = fmaf(bx1 * pw1, Bs, acc1[s]);
                    pw0 *= r0; pw1 *= r1;
                }
            } else {
                #pragma unroll
                for (int s = 0; s < 16; s++) {
                    float Bs = Bm[a * 16 + s];
                    acc0[s] = fmaf(bx0 * __expf(As0[s] * cum0), Bs, acc0[s]);
                    acc1[s] = fmaf(bx1 * __expf(As1[s] * cum1), Bs, acc1[s]);
                }
            }
            cum0 += da0; cum1 += da1;
            a = (a - 1) >> 1;
        }
    }

    float xn0 = bf2f(x_bf[(size_t)n * 512 + d0]);
    float xn1 = bf2f(x_bf[(size_t)n * 512 + d1]);
    float y0 = Dv[d0] * xn0, y1 = Dv[d1] * xn1;
    #pragma unroll
    for (int s = 0; s < 16; s++) {
        float Cs = Cm[(size_t)n * 16 + s];
        y0 += Cs * acc0[s];
        y1 += Cs * acc1[s];
    }

    float s1 = y0 + y1;
    float s2 = y0 * y0 + y1 * y1;
    #pragma unroll
    for (int off = 32; off > 0; off >>= 1) {
        s1 += __shfl_xor(s1, off);
        s2 += __shfl_xor(s2, off);
    }
    __shared__ float red[8];
    int wid = t >> 6, lane = t & 63;
    if (lane == 0) { red[wid] = s1; red[wid + 4] = s2; }
    __syncthreads();
    float S1 = red[0] + red[1] + red[2] + red[3];
    float S2 = red[4] + red[5] + red[6] + red[7];
    float mu = S1 * (1.f / 512.f);
    float var = S2 * (1.f / 512.f) - mu * mu;
    float inv = rsqrtf(var + 1e-5f);
    out[(size_t)n * 512 + d0] = (y0 - mu) * inv * gamma[d0] + beta[d0];
    out[(size_t)n * 512 + d1] = (y1 - mu) * inv * gamma[d1] + beta[d1];
}

extern "C" void kernel_launch(void* const* d_in, const int* in_sizes, int n_in,
                              void* d_out, int out_size, void* d_ws, size_t ws_size,
                              hipStream_t stream) {
    const float* s_in   = (const float*)d_in[0];
    const float* w      = (const float*)d_in[1];
    const float* W_in    = (const float*)d_in[4];
    const float* b_in    = (const float*)d_in[5];
    const float* W_delta = (const float*)d_in[6];
    const float* b_delta = (const float*)d_in[7];
    const float* W_w     = (const float*)d_in[8];
    const float* b_w     = (const float*)d_in[9];
    const float* A_log   = (const float*)d_in[10];
    const float* Dv      = (const float*)d_in[11];
    const float* W_B     = (const float*)d_in[12];
    const float* b_B     = (const float*)d_in[13];
    const float* W_C     = (const float*)d_in[14];
    const float* b_C     = (const float*)d_in[15];
    const float* gamma   = (const float*)d_in[16];
    const float* beta    = (const float*)d_in[17];
    float* out = (float*)d_out;

    const int Nn = in_sizes[1];           // 16383

    float* ws    = (float*)d_ws;
    float* lw    = ws;                                      // 16384
    float* delta = lw + MPAD;                               // 16384*512 fp32
    float* Bm    = delta + (size_t)MPAD * 512;              // 16384*16
    float* Cm    = Bm + (size_t)MPAD * 16;                  // 16384*16
    float* H9    = Cm + (size_t)MPAD * 16;                  // 512*512*16
    unsigned short* s_bf  = (unsigned short*)(H9 + (size_t)N_CKPT * 512 * 16);  // 16384*512
    unsigned short* x_bf  = s_bf + (size_t)MPAD * 512;      // 16384*512
    unsigned short* Win_bf = x_bf + (size_t)MPAD * 512;     // 512*512
    unsigned short* Wd_bf  = Win_bf + 512 * 512;            // 512*512

    prep_kernel<<<MPAD + 1024, 256, 0, stream>>>(s_in, w, W_in, W_delta,
                                                 s_bf, lw, Win_bf, Wd_bf, Nn);

    dim3 gg(4, 128);
    // x_bf = bf16( [s|lw] @ W_in.T + b_in )
    gemm_mfma<<<gg, 256, 0, stream>>>(s_bf, Win_bf, nullptr, x_bf,
                                      b_in, lw, W_in + 512, 513, nullptr, 0);
    // delta = softplus(x @ W_delta.T + b_delta) * sigmoid(lw*W_w + b_w)
    gemm_mfma<<<gg, 256, 0, stream>>>(x_bf, Wd_bf, delta, nullptr,
                                      b_delta, lw, W_w, 1, b_w, 1);

    bc_kernel<<<Nn, 256, 0, stream>>>(x_bf, W_B, b_B, W_C, b_C, Bm, Cm, Nn);

    ckpt_kernel<<<N_CKPT, 256, 0, stream>>>(x_bf, delta, Bm, A_log, H9);

    scan_kernel<<<Nn, 256, 0, stream>>>(x_bf, delta, Bm, Cm, H9, A_log, Dv,
                                        gamma, beta, out, Nn);
}

// Round 4
// 342.423 us; speedup vs baseline: 2.0514x; 1.2894x over previous
//
#include <hip/hip_runtime.h>
#include <hip/hip_bf16.h>
#include <math.h>

#define D_SSM 512
#define D_STATE 16
#define CKPT_BASE 511     // first index of level 9
#define CKPT_END 1023     // first index of level 10
#define N_CKPT 512        // nodes at level 9
#define MPAD 16384

typedef __attribute__((ext_vector_type(8))) short short8;
typedef __attribute__((ext_vector_type(4))) float floatx4;

__device__ __forceinline__ unsigned short f2bf(float f) {
    unsigned int u = __float_as_uint(f);
    unsigned int r = (u + 0x7fffu + ((u >> 16) & 1u)) >> 16;
    return (unsigned short)r;
}
__device__ __forceinline__ float bf2f(unsigned short u) {
    return __uint_as_float(((unsigned int)u) << 16);
}
__device__ __forceinline__ void g2lds16(const void* g, void* l) {
    __builtin_amdgcn_global_load_lds(
        (const __attribute__((address_space(1))) void*)g,
        (__attribute__((address_space(3))) void*)l, 16, 0, 0);
}

// ---------------- prep: cast s/W_in/W_delta to bf16, compute lw ----------------
__global__ __launch_bounds__(256) void prep_kernel(
    const float* __restrict__ s, const float* __restrict__ w,
    const float* __restrict__ W_in, const float* __restrict__ W_delta,
    unsigned short* __restrict__ s_bf, float* __restrict__ lw,
    unsigned short* __restrict__ Win_bf, unsigned short* __restrict__ Wd_bf, int Nn)
{
    const int b = blockIdx.x, t = threadIdx.x;
    if (b < MPAD) {
        unsigned int pack = 0;
        if (b < Nn) {
            float2 sv = *(const float2*)(s + (size_t)b * 512 + t * 2);
            pack = (unsigned int)f2bf(sv.x) | ((unsigned int)f2bf(sv.y) << 16);
        }
        *(unsigned int*)(s_bf + (size_t)b * 512 + t * 2) = pack;
        if (t == 0) lw[b] = (b < Nn) ? logf(w[b] + 1e-6f) : 0.f;
    } else if (b < MPAD + 512) {
        int c = b - MPAD;
        float a0 = W_in[(size_t)c * 513 + t * 2];
        float a1 = W_in[(size_t)c * 513 + t * 2 + 1];
        *(unsigned int*)(Win_bf + (size_t)c * 512 + t * 2) =
            (unsigned int)f2bf(a0) | ((unsigned int)f2bf(a1) << 16);
    } else {
        int c = b - MPAD - 512;
        float2 wv = *(const float2*)(W_delta + (size_t)c * 512 + t * 2);
        *(unsigned int*)(Wd_bf + (size_t)c * 512 + t * 2) =
            (unsigned int)f2bf(wv.x) | ((unsigned int)f2bf(wv.y) << 16);
    }
}

// ---------------- bf16 MFMA GEMM with XOR-swizzled LDS ----------------
// mode 0: o = z + bias[c] + lw[r]*wcol[c*wcol_stride]; store bf16 -> outbf
// mode 1: o = softplus(z+bias[c]) * sigmoid(lw[r]*wcol[c]+bw[c]); store fp32 -> outf
__global__ __launch_bounds__(256) void gemm_mfma(
    const unsigned short* __restrict__ Abf,   // [16384][512] bf16
    const unsigned short* __restrict__ Wbf,   // [512][512] bf16
    float* __restrict__ outf,
    unsigned short* __restrict__ outbf,
    const float* __restrict__ bias,
    const float* __restrict__ lw,
    const float* __restrict__ wcol, int wcol_stride,
    const float* __restrict__ bw,
    int mode)
{
    __shared__ __align__(16) short As[128 * 32];
    __shared__ __align__(16) short Bs[128 * 32];
    const int tid = threadIdx.x;
    const int wave = tid >> 6, lane = tid & 63;
    const int row0 = blockIdx.y * 128;
    const int col0 = blockIdx.x * 128;
    const int wr = (wave >> 1) * 64;
    const int wc = (wave & 1) * 64;

    floatx4 acc[4][4] = {};

    // staging address: lane L -> row srow, swizzled k-group sg (LDS slot = base + L*16 fixed by HW)
    const int srow = lane >> 2;                       // 0..15
    const int sg   = (lane & 3) ^ ((srow >> 1) & 3);  // XOR swizzle
    const int scol = sg * 8;

    for (int k0 = 0; k0 < 512; k0 += 32) {
        #pragma unroll
        for (int j = 0; j < 2; j++) {
            int c = wave * 2 + j;            // chunk 0..7 -> rows c*16..c*16+15
            int r = c * 16 + srow;
            g2lds16(Abf + (size_t)(row0 + r) * 512 + k0 + scol, (char*)As + c * 1024);
            g2lds16(Wbf + (size_t)(col0 + r) * 512 + k0 + scol, (char*)Bs + c * 1024);
        }
        __syncthreads();

        short8 af[4], bfr[4];
        #pragma unroll
        for (int i = 0; i < 4; i++) {
            int m = wr + i * 16 + (lane & 15);
            int gm = (lane >> 4) ^ ((m >> 1) & 3);
            af[i] = *(const short8*)&As[m * 32 + gm * 8];
            int n = wc + i * 16 + (lane & 15);
            int gn = (lane >> 4) ^ ((n >> 1) & 3);
            bfr[i] = *(const short8*)&Bs[n * 32 + gn * 8];
        }
        #pragma unroll
        for (int i = 0; i < 4; i++)
            #pragma unroll
            for (int j2 = 0; j2 < 4; j2++)
                acc[i][j2] = __builtin_amdgcn_mfma_f32_16x16x32_bf16(af[i], bfr[j2], acc[i][j2], 0, 0, 0);
        __syncthreads();
    }

    #pragma unroll
    for (int i = 0; i < 4; i++) {
        #pragma unroll
        for (int reg = 0; reg < 4; reg++) {
            int r = row0 + wr + i * 16 + (lane >> 4) * 4 + reg;
            float lwr = lw[r];
            #pragma unroll
            for (int j = 0; j < 4; j++) {
                int c = col0 + wc + j * 16 + (lane & 15);
                float z = acc[i][j][reg] + bias[c];
                if (mode == 0) {
                    float o = z + lwr * wcol[(size_t)c * wcol_stride];
                    outbf[(size_t)r * 512 + c] = f2bf(o);
                } else {
                    float sp = (z > 15.f) ? z : log1pf(__expf(z));
                    float sg2 = 1.f / (1.f + __expf(-(lwr * wcol[c] + bw[c])));
                    outf[(size_t)r * 512 + c] = sp * sg2;
                }
            }
        }
    }
}

// ---------------- B/C projections (x in bf16) ----------------
__global__ __launch_bounds__(256) void bc_kernel(
    const unsigned short* __restrict__ x_bf,
    const float* __restrict__ W_B, const float* __restrict__ b_B,
    const float* __restrict__ W_C, const float* __restrict__ b_C,
    float* __restrict__ Bm, float* __restrict__ Cm, int Nn)
{
    __shared__ float xs[512];
    const int n = blockIdx.x;
    const int t = threadIdx.x;
    xs[t] = bf2f(x_bf[(size_t)n * 512 + t]);
    xs[t + 256] = bf2f(x_bf[(size_t)n * 512 + t + 256]);
    __syncthreads();
    const int oid = t >> 3;
    const int part = t & 7;
    const float* Wrow = (oid < 16) ? (W_B + (size_t)oid * 512) : (W_C + (size_t)(oid - 16) * 512);
    float sum = 0.f;
    for (int i = part; i < 512; i += 8) sum += Wrow[i] * xs[i];
    sum += __shfl_xor(sum, 1);
    sum += __shfl_xor(sum, 2);
    sum += __shfl_xor(sum, 4);
    if (part == 0) {
        if (oid < 16) Bm[(size_t)n * 16 + oid] = sum + b_B[oid];
        else          Cm[(size_t)n * 16 + (oid - 16)] = sum + b_C[oid - 16];
    }
}

// fast path valid when As[s] == (s+1)*As[0]
__device__ __forceinline__ bool geo_check(const float* As) {
    bool ok = true;
    #pragma unroll
    for (int s = 1; s < 16; s++) {
        float want = (float)(s + 1) * As[0];
        ok = ok && (fabsf(As[s] - want) <= 1e-4f * (float)(s + 1));
    }
    return ok;
}

// ---------------- checkpoint kernel: H for all level-9 nodes ----------------
__global__ __launch_bounds__(256) void ckpt_kernel(
    const unsigned short* __restrict__ x_bf, const float* __restrict__ delta,
    const float* __restrict__ Bm, const float* __restrict__ A_log,
    float* __restrict__ H9)
{
    const int n9 = blockIdx.x;
    const int t = threadIdx.x;
    const int d0 = t, d1 = t + 256;

    float As0[16], As1[16], acc0[16], acc1[16];
    #pragma unroll
    for (int s = 0; s < 16; s++) {
        As0[s] = -__expf(A_log[d0 * 16 + s]);
        As1[s] = -__expf(A_log[d1 * 16 + s]);
        acc0[s] = 0.f; acc1[s] = 0.f;
    }
    const bool fast = geo_check(As0) && geo_check(As1);

    float cum0 = 0.f, cum1 = 0.f;
    int a = CKPT_BASE + n9;
    while (a >= 0) {
        float da0 = delta[(size_t)a * 512 + d0];
        float da1 = delta[(size_t)a * 512 + d1];
        float bx0 = da0 * bf2f(x_bf[(size_t)a * 512 + d0]);
        float bx1 = da1 * bf2f(x_bf[(size_t)a * 512 + d1]);
        if (fast) {
            float r0 = __expf(As0[0] * cum0);
            float r1 = __expf(As1[0] * cum1);
            float pw0 = r0, pw1 = r1;
            #pragma unroll
            for (int s = 0; s < 16; s++) {
                float Bs = Bm[a * 16 + s];
                acc0[s] = fmaf(bx0 * pw0, Bs, acc0[s]);
                acc1[s] = fmaf(bx1 * pw1, Bs, acc1[s]);
                pw0 *= r0; pw1 *= r1;
            }
        } else {
            #pragma unroll
            for (int s = 0; s < 16; s++) {
                float Bs = Bm[a * 16 + s];
                acc0[s] = fmaf(bx0 * __expf(As0[s] * cum0), Bs, acc0[s]);
                acc1[s] = fmaf(bx1 * __expf(As1[s] * cum1), Bs, acc1[s]);
            }
        }
        cum0 += da0; cum1 += da1;
        a = (a - 1) >> 1;
    }

    float* p0 = H9 + ((size_t)n9 * 512 + d0) * 16;
    float* p1 = H9 + ((size_t)n9 * 512 + d1) * 16;
    #pragma unroll
    for (int s = 0; s < 16; s++) { p0[s] = acc0[s]; p1[s] = acc1[s]; }
}

// ---------------- shallow scan (nodes 0..510, levels 0..8): walk + LN ----------------
__global__ __launch_bounds__(256) void scan_shallow(
    const unsigned short* __restrict__ x_bf, const float* __restrict__ delta,
    const float* __restrict__ Bm, const float* __restrict__ Cm,
    const float* __restrict__ A_log, const float* __restrict__ Dv,
    const float* __restrict__ gamma, const float* __restrict__ beta,
    float* __restrict__ out)
{
    const int n = blockIdx.x;
    const int t = threadIdx.x;
    const int d0 = t, d1 = t + 256;

    float As0[16], As1[16], acc0[16], acc1[16];
    #pragma unroll
    for (int s = 0; s < 16; s++) {
        As0[s] = -__expf(A_log[d0 * 16 + s]);
        As1[s] = -__expf(A_log[d1 * 16 + s]);
        acc0[s] = 0.f; acc1[s] = 0.f;
    }
    const bool fast = geo_check(As0) && geo_check(As1);

    float cum0 = 0.f, cum1 = 0.f;
    int a = n;
    while (a >= 0) {
        float da0 = delta[(size_t)a * 512 + d0];
        float da1 = delta[(size_t)a * 512 + d1];
        float bx0 = da0 * bf2f(x_bf[(size_t)a * 512 + d0]);
        float bx1 = da1 * bf2f(x_bf[(size_t)a * 512 + d1]);
        if (fast) {
            float r0 = __expf(As0[0] * cum0);
            float r1 = __expf(As1[0] * cum1);
            float pw0 = r0, pw1 = r1;
            #pragma unroll
            for (int s = 0; s < 16; s++) {
                float Bs = Bm[a * 16 + s];
                acc0[s] = fmaf(bx0 * pw0, Bs, acc0[s]);
                acc1[s] = fmaf(bx1 * pw1, Bs, acc1[s]);
                pw0 *= r0; pw1 *= r1;
            }
        } else {
            #pragma unroll
            for (int s = 0; s < 16; s++) {
                float Bs = Bm[a * 16 + s];
                acc0[s] = fmaf(bx0 * __expf(As0[s] * cum0), Bs, acc0[s]);
                acc1[s] = fmaf(bx1 * __expf(As1[s] * cum1), Bs, acc1[s]);
            }
        }
        cum0 += da0; cum1 += da1;
        a = (a - 1) >> 1;
    }

    float xn0 = bf2f(x_bf[(size_t)n * 512 + d0]);
    float xn1 = bf2f(x_bf[(size_t)n * 512 + d1]);
    float y0 = Dv[d0] * xn0, y1 = Dv[d1] * xn1;
    #pragma unroll
    for (int s = 0; s < 16; s++) {
        float Cs = Cm[(size_t)n * 16 + s];
        y0 += Cs * acc0[s];
        y1 += Cs * acc1[s];
    }

    float s1 = y0 + y1;
    float s2 = y0 * y0 + y1 * y1;
    #pragma unroll
    for (int off = 32; off > 0; off >>= 1) {
        s1 += __shfl_xor(s1, off);
        s2 += __shfl_xor(s2, off);
    }
    __shared__ float red[8];
    int wid = t >> 6, lane = t & 63;
    if (lane == 0) { red[wid] = s1; red[wid + 4] = s2; }
    __syncthreads();
    float S1 = red[0] + red[1] + red[2] + red[3];
    float S2 = red[4] + red[5] + red[6] + red[7];
    float mu = S1 * (1.f / 512.f);
    float var = S2 * (1.f / 512.f) - mu * mu;
    float inv = rsqrtf(var + 1e-5f);
    out[(size_t)n * 512 + d0] = (y0 - mu) * inv * gamma[d0] + beta[d0];
    out[(size_t)n * 512 + d1] = (y1 - mu) * inv * gamma[d1] + beta[d1];
}

// ---------------- deep scan: one block per level-9 subtree, DFS forward sweep ----------------
// 512 threads, 1 channel each. Streams every delta/x row exactly once; H9 row read once.
__global__ __launch_bounds__(512) void scan_deep(
    const unsigned short* __restrict__ x_bf, const float* __restrict__ delta,
    const float* __restrict__ Bm, const float* __restrict__ Cm,
    const float* __restrict__ H9,
    const float* __restrict__ A_log, const float* __restrict__ Dv,
    const float* __restrict__ gamma, const float* __restrict__ beta,
    float* __restrict__ out)
{
    __shared__ float Y[31][512];
    __shared__ int nid[31];
    const int p = blockIdx.x;        // subtree (level-9 root) id
    const int d = threadIdx.x;       // channel
    const int a9 = CKPT_BASE + p;

    float As0 = -__expf(A_log[d * 16]);
    bool fast = true;
    #pragma unroll
    for (int s = 1; s < 16; s++) {
        float As = -__expf(A_log[d * 16 + s]);
        fast = fast && (fabsf(As - (float)(s + 1) * As0) <= 1e-4f * (float)(s + 1));
    }

    float H9v[16];
    #pragma unroll
    for (int s = 0; s < 16; s++) H9v[s] = H9[((size_t)p * 512 + d) * 16 + s];

    // root (level-9 node) readout directly from H9
    {
        float xv = bf2f(x_bf[(size_t)a9 * 512 + d]);
        float y = Dv[d] * xv;
        #pragma unroll
        for (int s = 0; s < 16; s++) y = fmaf(Cm[(size_t)a9 * 16 + s], H9v[s], y);
        Y[0][d] = y;
        if (d == 0) nid[0] = a9;
    }

    auto step = [&](int n, const float* Hp, float* Hc, int slot) {
        float dlt = delta[(size_t)n * 512 + d];
        float xv = bf2f(x_bf[(size_t)n * 512 + d]);
        float bx = dlt * xv;
        const float* Bn = Bm + (size_t)n * 16;
        const float* Cn = Cm + (size_t)n * 16;
        float y = Dv[d] * xv;
        if (fast) {
            float r = __expf(As0 * dlt);
            float pw = r;
            #pragma unroll
            for (int s = 0; s < 16; s++) {
                Hc[s] = fmaf(pw, Hp[s], bx * Bn[s]);
                y = fmaf(Cn[s], Hc[s], y);
                pw *= r;
            }
        } else {
            #pragma unroll
            for (int s = 0; s < 16; s++) {
                float Ab = __expf(dlt * (-__expf(A_log[d * 16 + s])));
                Hc[s] = fmaf(Ab, Hp[s], bx * Bn[s]);
                y = fmaf(Cn[s], Hc[s], y);
            }
        }
        Y[slot][d] = y;
        if (d == 0) nid[slot] = n;
    };

    float H10[16], H11[16], H12[16], H13[16];
    int slot = 1;
    #pragma unroll
    for (int c0 = 0; c0 < 2; c0++) {
        int n10 = 2 * a9 + 1 + c0;
        step(n10, H9v, H10, slot++);
        #pragma unroll
        for (int c1 = 0; c1 < 2; c1++) {
            int n11 = 2 * n10 + 1 + c1;
            step(n11, H10, H11, slot++);
            #pragma unroll
            for (int c2 = 0; c2 < 2; c2++) {
                int n12 = 2 * n11 + 1 + c2;
                step(n12, H11, H12, slot++);
                #pragma unroll
                for (int c3 = 0; c3 < 2; c3++) {
                    int n13 = 2 * n12 + 1 + c3;
                    step(n13, H12, H13, slot++);
                }
            }
        }
    }
    __syncthreads();

    // LayerNorm: wave w handles slots w, w+8, ...
    const int w = d >> 6, lane = d & 63;
    for (int i = w; i < 31; i += 8) {
        int n = nid[i];
        float v[8]; float s1 = 0.f, s2 = 0.f;
        #pragma unroll
        for (int k = 0; k < 8; k++) {
            v[k] = Y[i][lane + 64 * k];
            s1 += v[k]; s2 += v[k] * v[k];
        }
        #pragma unroll
        for (int off = 32; off > 0; off >>= 1) {
            s1 += __shfl_xor(s1, off);
            s2 += __shfl_xor(s2, off);
        }
        float mu = s1 * (1.f / 512.f);
        float inv = rsqrtf(s2 * (1.f / 512.f) - mu * mu + 1e-5f);
        #pragma unroll
        for (int k = 0; k < 8; k++) {
            int ch = lane + 64 * k;
            out[(size_t)n * 512 + ch] = (v[k] - mu) * inv * gamma[ch] + beta[ch];
        }
    }
}

extern "C" void kernel_launch(void* const* d_in, const int* in_sizes, int n_in,
                              void* d_out, int out_size, void* d_ws, size_t ws_size,
                              hipStream_t stream) {
    const float* s_in   = (const float*)d_in[0];
    const float* w      = (const float*)d_in[1];
    const float* W_in    = (const float*)d_in[4];
    const float* b_in    = (const float*)d_in[5];
    const float* W_delta = (const float*)d_in[6];
    const float* b_delta = (const float*)d_in[7];
    const float* W_w     = (const float*)d_in[8];
    const float* b_w     = (const float*)d_in[9];
    const float* A_log   = (const float*)d_in[10];
    const float* Dv      = (const float*)d_in[11];
    const float* W_B     = (const float*)d_in[12];
    const float* b_B     = (const float*)d_in[13];
    const float* W_C     = (const float*)d_in[14];
    const float* b_C     = (const float*)d_in[15];
    const float* gamma   = (const float*)d_in[16];
    const float* beta    = (const float*)d_in[17];
    float* out = (float*)d_out;

    const int Nn = in_sizes[1];           // 16383

    float* ws    = (float*)d_ws;
    float* lw    = ws;                                      // 16384
    float* delta = lw + MPAD;                               // 16384*512 fp32
    float* Bm    = delta + (size_t)MPAD * 512;              // 16384*16
    float* Cm    = Bm + (size_t)MPAD * 16;                  // 16384*16
    float* H9    = Cm + (size_t)MPAD * 16;                  // 512*512*16
    unsigned short* s_bf  = (unsigned short*)(H9 + (size_t)N_CKPT * 512 * 16);  // 16384*512
    unsigned short* x_bf  = s_bf + (size_t)MPAD * 512;      // 16384*512
    unsigned short* Win_bf = x_bf + (size_t)MPAD * 512;     // 512*512
    unsigned short* Wd_bf  = Win_bf + 512 * 512;            // 512*512

    prep_kernel<<<MPAD + 1024, 256, 0, stream>>>(s_in, w, W_in, W_delta,
                                                 s_bf, lw, Win_bf, Wd_bf, Nn);

    dim3 gg(4, 128);
    gemm_mfma<<<gg, 256, 0, stream>>>(s_bf, Win_bf, nullptr, x_bf,
                                      b_in, lw, W_in + 512, 513, nullptr, 0);
    gemm_mfma<<<gg, 256, 0, stream>>>(x_bf, Wd_bf, delta, nullptr,
                                      b_delta, lw, W_w, 1, b_w, 1);

    bc_kernel<<<Nn, 256, 0, stream>>>(x_bf, W_B, b_B, W_C, b_C, Bm, Cm, Nn);

    ckpt_kernel<<<N_CKPT, 256, 0, stream>>>(x_bf, delta, Bm, A_log, H9);

    scan_shallow<<<CKPT_BASE, 256, 0, stream>>>(x_bf, delta, Bm, Cm, A_log, Dv,
                                                gamma, beta, out);

    scan_deep<<<N_CKPT, 512, 0, stream>>>(x_bf, delta, Bm, Cm, H9, A_log, Dv,
                                          gamma, beta, out);
}

// Round 5
// 276.840 us; speedup vs baseline: 2.5374x; 1.2369x over previous
//
#include <hip/hip_runtime.h>
#include <hip/hip_bf16.h>
#include <math.h>

#define D_SSM 512
#define D_STATE 16
#define CKPT_BASE 511     // first index of level 9
#define CKPT_END 1023     // first index of level 10
#define N_CKPT 512        // nodes at level 9
#define MPAD 16384

typedef __attribute__((ext_vector_type(8))) short short8;
typedef __attribute__((ext_vector_type(4))) float floatx4;

__device__ __forceinline__ unsigned short f2bf(float f) {
    unsigned int u = __float_as_uint(f);
    unsigned int r = (u + 0x7fffu + ((u >> 16) & 1u)) >> 16;
    return (unsigned short)r;
}
__device__ __forceinline__ float bf2f(unsigned short u) {
    return __uint_as_float(((unsigned int)u) << 16);
}
__device__ __forceinline__ void g2lds16(const void* g, void* l) {
    __builtin_amdgcn_global_load_lds(
        (const __attribute__((address_space(1))) void*)g,
        (__attribute__((address_space(3))) void*)l, 16, 0, 0);
}

// ---------------- prep: cast s/W_in/W_delta/W_B/W_C to bf16, compute lw ----------------
__global__ __launch_bounds__(256) void prep_kernel(
    const float* __restrict__ s, const float* __restrict__ w,
    const float* __restrict__ W_in, const float* __restrict__ W_delta,
    const float* __restrict__ W_B, const float* __restrict__ W_C,
    unsigned short* __restrict__ s_bf, float* __restrict__ lw,
    unsigned short* __restrict__ Win_bf, unsigned short* __restrict__ Wd_bf,
    unsigned short* __restrict__ Wbc_bf, int Nn)
{
    const int b = blockIdx.x, t = threadIdx.x;
    if (b < MPAD) {
        unsigned int pack = 0;
        if (b < Nn) {
            float2 sv = *(const float2*)(s + (size_t)b * 512 + t * 2);
            pack = (unsigned int)f2bf(sv.x) | ((unsigned int)f2bf(sv.y) << 16);
        }
        *(unsigned int*)(s_bf + (size_t)b * 512 + t * 2) = pack;
        if (t == 0) lw[b] = (b < Nn) ? logf(w[b] + 1e-6f) : 0.f;
    } else if (b < MPAD + 512) {
        int c = b - MPAD;
        float a0 = W_in[(size_t)c * 513 + t * 2];
        float a1 = W_in[(size_t)c * 513 + t * 2 + 1];
        *(unsigned int*)(Win_bf + (size_t)c * 512 + t * 2) =
            (unsigned int)f2bf(a0) | ((unsigned int)f2bf(a1) << 16);
    } else if (b < MPAD + 1024) {
        int c = b - MPAD - 512;
        float2 wv = *(const float2*)(W_delta + (size_t)c * 512 + t * 2);
        *(unsigned int*)(Wd_bf + (size_t)c * 512 + t * 2) =
            (unsigned int)f2bf(wv.x) | ((unsigned int)f2bf(wv.y) << 16);
    } else {
        int c = b - MPAD - 1024;   // 0..31: rows 0..15 = W_B, 16..31 = W_C
        const float* src = (c < 16) ? (W_B + (size_t)c * 512) : (W_C + (size_t)(c - 16) * 512);
        float2 wv = *(const float2*)(src + t * 2);
        *(unsigned int*)(Wbc_bf + (size_t)c * 512 + t * 2) =
            (unsigned int)f2bf(wv.x) | ((unsigned int)f2bf(wv.y) << 16);
    }
}

// ---------------- bf16 MFMA GEMM with XOR-swizzled LDS ----------------
// mode 0: o = z + bias[c] + lw[r]*wcol[c*wcol_stride]; store bf16 -> outbf
// mode 1: o = softplus(z+bias[c]) * sigmoid(lw[r]*wcol[c]+bw[c]); store fp32 -> outf
__global__ __launch_bounds__(256) void gemm_mfma(
    const unsigned short* __restrict__ Abf,   // [16384][512] bf16
    const unsigned short* __restrict__ Wbf,   // [512][512] bf16
    float* __restrict__ outf,
    unsigned short* __restrict__ outbf,
    const float* __restrict__ bias,
    const float* __restrict__ lw,
    const float* __restrict__ wcol, int wcol_stride,
    const float* __restrict__ bw,
    int mode)
{
    __shared__ __align__(16) short As[128 * 32];
    __shared__ __align__(16) short Bs[128 * 32];
    const int tid = threadIdx.x;
    const int wave = tid >> 6, lane = tid & 63;
    const int row0 = blockIdx.y * 128;
    const int col0 = blockIdx.x * 128;
    const int wr = (wave >> 1) * 64;
    const int wc = (wave & 1) * 64;

    floatx4 acc[4][4] = {};

    const int srow = lane >> 2;                       // 0..15
    const int sg   = (lane & 3) ^ ((srow >> 1) & 3);  // XOR swizzle
    const int scol = sg * 8;

    for (int k0 = 0; k0 < 512; k0 += 32) {
        #pragma unroll
        for (int j = 0; j < 2; j++) {
            int c = wave * 2 + j;
            int r = c * 16 + srow;
            g2lds16(Abf + (size_t)(row0 + r) * 512 + k0 + scol, (char*)As + c * 1024);
            g2lds16(Wbf + (size_t)(col0 + r) * 512 + k0 + scol, (char*)Bs + c * 1024);
        }
        __syncthreads();

        short8 af[4], bfr[4];
        #pragma unroll
        for (int i = 0; i < 4; i++) {
            int m = wr + i * 16 + (lane & 15);
            int gm = (lane >> 4) ^ ((m >> 1) & 3);
            af[i] = *(const short8*)&As[m * 32 + gm * 8];
            int n = wc + i * 16 + (lane & 15);
            int gn = (lane >> 4) ^ ((n >> 1) & 3);
            bfr[i] = *(const short8*)&Bs[n * 32 + gn * 8];
        }
        #pragma unroll
        for (int i = 0; i < 4; i++)
            #pragma unroll
            for (int j2 = 0; j2 < 4; j2++)
                acc[i][j2] = __builtin_amdgcn_mfma_f32_16x16x32_bf16(af[i], bfr[j2], acc[i][j2], 0, 0, 0);
        __syncthreads();
    }

    #pragma unroll
    for (int i = 0; i < 4; i++) {
        #pragma unroll
        for (int reg = 0; reg < 4; reg++) {
            int r = row0 + wr + i * 16 + (lane >> 4) * 4 + reg;
            float lwr = lw[r];
            #pragma unroll
            for (int j = 0; j < 4; j++) {
                int c = col0 + wc + j * 16 + (lane & 15);
                float z = acc[i][j][reg] + bias[c];
                if (mode == 0) {
                    float o = z + lwr * wcol[(size_t)c * wcol_stride];
                    outbf[(size_t)r * 512 + c] = f2bf(o);
                } else {
                    float sp = (z > 15.f) ? z : log1pf(__expf(z));
                    float sg2 = 1.f / (1.f + __expf(-(lwr * wcol[c] + bw[c])));
                    outf[(size_t)r * 512 + c] = sp * sg2;
                }
            }
        }
    }
}

// ---------------- B/C via skinny MFMA GEMM: [16384x512] @ [512x32] ----------------
// Wbc rows 0..15 = W_B, 16..31 = W_C. Bm[n,s] = x@W_B.T + b_B, Cm likewise.
__global__ __launch_bounds__(256) void bc_gemm(
    const unsigned short* __restrict__ Abf,    // x_bf [16384][512]
    const unsigned short* __restrict__ Wbc,    // [32][512] bf16
    const float* __restrict__ b_B, const float* __restrict__ b_C,
    float* __restrict__ Bm, float* __restrict__ Cm)
{
    __shared__ __align__(16) short As[128 * 32];
    __shared__ __align__(16) short Ws[32 * 512];
    const int tid = threadIdx.x;
    const int wave = tid >> 6, lane = tid & 63;
    const int row0 = blockIdx.x * 128;
    const int wr = wave * 32;

    // stage full weight matrix once, swizzled: slot(n, kg^(n&7)) <- global kgroup kg
    for (int i = 0; i < 8; i++) {
        int fg = i * 256 + tid;          // flat k-group id, 0..2047
        int n = fg >> 6, kgg = fg & 63;
        short8 v = *(const short8*)(Wbc + (size_t)n * 512 + kgg * 8);
        *(short8*)&Ws[n * 512 + ((kgg ^ (n & 7)) * 8)] = v;
    }

    floatx4 acc[2][2] = {};

    const int srow = lane >> 2;
    const int sgz  = (lane & 3) ^ ((srow >> 1) & 3);
    const int scol = sgz * 8;

    for (int k0 = 0; k0 < 512; k0 += 32) {
        #pragma unroll
        for (int j = 0; j < 2; j++) {
            int c = wave * 2 + j;
            int r = c * 16 + srow;
            g2lds16(Abf + (size_t)(row0 + r) * 512 + k0 + scol, (char*)As + c * 1024);
        }
        __syncthreads();

        short8 af[2], bfr[2];
        #pragma unroll
        for (int i = 0; i < 2; i++) {
            int m = wr + i * 16 + (lane & 15);
            int gm = (lane >> 4) ^ ((m >> 1) & 3);
            af[i] = *(const short8*)&As[m * 32 + gm * 8];
        }
        #pragma unroll
        for (int j = 0; j < 2; j++) {
            int n = j * 16 + (lane & 15);
            int Gg = (k0 >> 3) + (lane >> 4);
            bfr[j] = *(const short8*)&Ws[n * 512 + ((Gg ^ (n & 7)) * 8)];
        }
        #pragma unroll
        for (int i = 0; i < 2; i++)
            #pragma unroll
            for (int j = 0; j < 2; j++)
                acc[i][j] = __builtin_amdgcn_mfma_f32_16x16x32_bf16(af[i], bfr[j], acc[i][j], 0, 0, 0);
        __syncthreads();
    }

    const int s = lane & 15;
    #pragma unroll
    for (int i = 0; i < 2; i++) {
        #pragma unroll
        for (int reg = 0; reg < 4; reg++) {
            int r = row0 + wr + i * 16 + (lane >> 4) * 4 + reg;
            Bm[(size_t)r * 16 + s] = acc[i][0][reg] + b_B[s];
            Cm[(size_t)r * 16 + s] = acc[i][1][reg] + b_C[s];
        }
    }
}

// fast path valid when As[s] == (s+1)*As[0]
__device__ __forceinline__ bool geo_check(const float* As) {
    bool ok = true;
    #pragma unroll
    for (int s = 1; s < 16; s++) {
        float want = (float)(s + 1) * As[0];
        ok = ok && (fabsf(As[s] - want) <= 1e-4f * (float)(s + 1));
    }
    return ok;
}

// ---------------- checkpoint kernel: H for all level-9 nodes ----------------
__global__ __launch_bounds__(256) void ckpt_kernel(
    const unsigned short* __restrict__ x_bf, const float* __restrict__ delta,
    const float* __restrict__ Bm, const float* __restrict__ A_log,
    float* __restrict__ H9)
{
    const int n9 = blockIdx.x;
    const int t = threadIdx.x;
    const int d0 = t, d1 = t + 256;

    float As0[16], As1[16], acc0[16], acc1[16];
    #pragma unroll
    for (int s = 0; s < 16; s++) {
        As0[s] = -__expf(A_log[d0 * 16 + s]);
        As1[s] = -__expf(A_log[d1 * 16 + s]);
        acc0[s] = 0.f; acc1[s] = 0.f;
    }
    const bool fast = geo_check(As0) && geo_check(As1);

    float cum0 = 0.f, cum1 = 0.f;
    int a = CKPT_BASE + n9;
    while (a >= 0) {
        float da0 = delta[(size_t)a * 512 + d0];
        float da1 = delta[(size_t)a * 512 + d1];
        float bx0 = da0 * bf2f(x_bf[(size_t)a * 512 + d0]);
        float bx1 = da1 * bf2f(x_bf[(size_t)a * 512 + d1]);
        if (fast) {
            float r0 = __expf(As0[0] * cum0);
            float r1 = __expf(As1[0] * cum1);
            float pw0 = r0, pw1 = r1;
            #pragma unroll
            for (int s = 0; s < 16; s++) {
                float Bs = Bm[a * 16 + s];
                acc0[s] = fmaf(bx0 * pw0, Bs, acc0[s]);
                acc1[s] = fmaf(bx1 * pw1, Bs, acc1[s]);
                pw0 *= r0; pw1 *= r1;
            }
        } else {
            #pragma unroll
            for (int s = 0; s < 16; s++) {
                float Bs = Bm[a * 16 + s];
                acc0[s] = fmaf(bx0 * __expf(As0[s] * cum0), Bs, acc0[s]);
                acc1[s] = fmaf(bx1 * __expf(As1[s] * cum1), Bs, acc1[s]);
            }
        }
        cum0 += da0; cum1 += da1;
        a = (a - 1) >> 1;
    }

    float* p0 = H9 + ((size_t)n9 * 512 + d0) * 16;
    float* p1 = H9 + ((size_t)n9 * 512 + d1) * 16;
    #pragma unroll
    for (int s = 0; s < 16; s++) { p0[s] = acc0[s]; p1[s] = acc1[s]; }
}

// ---------------- shallow scan (nodes 0..510, levels 0..8): walk + LN ----------------
__global__ __launch_bounds__(256) void scan_shallow(
    const unsigned short* __restrict__ x_bf, const float* __restrict__ delta,
    const float* __restrict__ Bm, const float* __restrict__ Cm,
    const float* __restrict__ A_log, const float* __restrict__ Dv,
    const float* __restrict__ gamma, const float* __restrict__ beta,
    float* __restrict__ out)
{
    const int n = blockIdx.x;
    const int t = threadIdx.x;
    const int d0 = t, d1 = t + 256;

    float As0[16], As1[16], acc0[16], acc1[16];
    #pragma unroll
    for (int s = 0; s < 16; s++) {
        As0[s] = -__expf(A_log[d0 * 16 + s]);
        As1[s] = -__expf(A_log[d1 * 16 + s]);
        acc0[s] = 0.f; acc1[s] = 0.f;
    }
    const bool fast = geo_check(As0) && geo_check(As1);

    float cum0 = 0.f, cum1 = 0.f;
    int a = n;
    while (a >= 0) {
        float da0 = delta[(size_t)a * 512 + d0];
        float da1 = delta[(size_t)a * 512 + d1];
        float bx0 = da0 * bf2f(x_bf[(size_t)a * 512 + d0]);
        float bx1 = da1 * bf2f(x_bf[(size_t)a * 512 + d1]);
        if (fast) {
            float r0 = __expf(As0[0] * cum0);
            float r1 = __expf(As1[0] * cum1);
            float pw0 = r0, pw1 = r1;
            #pragma unroll
            for (int s = 0; s < 16; s++) {
                float Bs = Bm[a * 16 + s];
                acc0[s] = fmaf(bx0 * pw0, Bs, acc0[s]);
                acc1[s] = fmaf(bx1 * pw1, Bs, acc1[s]);
                pw0 *= r0; pw1 *= r1;
            }
        } else {
            #pragma unroll
            for (int s = 0; s < 16; s++) {
                float Bs = Bm[a * 16 + s];
                acc0[s] = fmaf(bx0 * __expf(As0[s] * cum0), Bs, acc0[s]);
                acc1[s] = fmaf(bx1 * __expf(As1[s] * cum1), Bs, acc1[s]);
            }
        }
        cum0 += da0; cum1 += da1;
        a = (a - 1) >> 1;
    }

    float xn0 = bf2f(x_bf[(size_t)n * 512 + d0]);
    float xn1 = bf2f(x_bf[(size_t)n * 512 + d1]);
    float y0 = Dv[d0] * xn0, y1 = Dv[d1] * xn1;
    #pragma unroll
    for (int s = 0; s < 16; s++) {
        float Cs = Cm[(size_t)n * 16 + s];
        y0 += Cs * acc0[s];
        y1 += Cs * acc1[s];
    }

    float s1 = y0 + y1;
    float s2 = y0 * y0 + y1 * y1;
    #pragma unroll
    for (int off = 32; off > 0; off >>= 1) {
        s1 += __shfl_xor(s1, off);
        s2 += __shfl_xor(s2, off);
    }
    __shared__ float red[8];
    int wid = t >> 6, lane = t & 63;
    if (lane == 0) { red[wid] = s1; red[wid + 4] = s2; }
    __syncthreads();
    float S1 = red[0] + red[1] + red[2] + red[3];
    float S2 = red[4] + red[5] + red[6] + red[7];
    float mu = S1 * (1.f / 512.f);
    float var = S2 * (1.f / 512.f) - mu * mu;
    float inv = rsqrtf(var + 1e-5f);
    out[(size_t)n * 512 + d0] = (y0 - mu) * inv * gamma[d0] + beta[d0];
    out[(size_t)n * 512 + d1] = (y1 - mu) * inv * gamma[d1] + beta[d1];
}

// ---------------- deep scan: one block per level-9 subtree, DFS forward sweep ----------------
__global__ __launch_bounds__(512) void scan_deep(
    const unsigned short* __restrict__ x_bf, const float* __restrict__ delta,
    const float* __restrict__ Bm, const float* __restrict__ Cm,
    const float* __restrict__ H9,
    const float* __restrict__ A_log, const float* __restrict__ Dv,
    const float* __restrict__ gamma, const float* __restrict__ beta,
    float* __restrict__ out)
{
    __shared__ float Y[31][512];
    __shared__ int nid[31];
    const int p = blockIdx.x;
    const int d = threadIdx.x;
    const int a9 = CKPT_BASE + p;

    float As0 = -__expf(A_log[d * 16]);
    bool fast = true;
    #pragma unroll
    for (int s = 1; s < 16; s++) {
        float As = -__expf(A_log[d * 16 + s]);
        fast = fast && (fabsf(As - (float)(s + 1) * As0) <= 1e-4f * (float)(s + 1));
    }

    float H9v[16];
    #pragma unroll
    for (int s = 0; s < 16; s++) H9v[s] = H9[((size_t)p * 512 + d) * 16 + s];

    {
        float xv = bf2f(x_bf[(size_t)a9 * 512 + d]);
        float y = Dv[d] * xv;
        #pragma unroll
        for (int s = 0; s < 16; s++) y = fmaf(Cm[(size_t)a9 * 16 + s], H9v[s], y);
        Y[0][d] = y;
        if (d == 0) nid[0] = a9;
    }

    auto step = [&](int n, const float* Hp, float* Hc, int slot) {
        float dlt = delta[(size_t)n * 512 + d];
        float xv = bf2f(x_bf[(size_t)n * 512 + d]);
        float bx = dlt * xv;
        const float* Bn = Bm + (size_t)n * 16;
        const float* Cn = Cm + (size_t)n * 16;
        float y = Dv[d] * xv;
        if (fast) {
            float r = __expf(As0 * dlt);
            float pw = r;
            #pragma unroll
            for (int s = 0; s < 16; s++) {
                Hc[s] = fmaf(pw, Hp[s], bx * Bn[s]);
                y = fmaf(Cn[s], Hc[s], y);
                pw *= r;
            }
        } else {
            #pragma unroll
            for (int s = 0; s < 16; s++) {
                float Ab = __expf(dlt * (-__expf(A_log[d * 16 + s])));
                Hc[s] = fmaf(Ab, Hp[s], bx * Bn[s]);
                y = fmaf(Cn[s], Hc[s], y);
            }
        }
        Y[slot][d] = y;
        if (d == 0) nid[slot] = n;
    };

    float H10[16], H11[16], H12[16], H13[16];
    int slot = 1;
    #pragma unroll
    for (int c0 = 0; c0 < 2; c0++) {
        int n10 = 2 * a9 + 1 + c0;
        step(n10, H9v, H10, slot++);
        #pragma unroll
        for (int c1 = 0; c1 < 2; c1++) {
            int n11 = 2 * n10 + 1 + c1;
            step(n11, H10, H11, slot++);
            #pragma unroll
            for (int c2 = 0; c2 < 2; c2++) {
                int n12 = 2 * n11 + 1 + c2;
                step(n12, H11, H12, slot++);
                #pragma unroll
                for (int c3 = 0; c3 < 2; c3++) {
                    int n13 = 2 * n12 + 1 + c3;
                    step(n13, H12, H13, slot++);
                }
            }
        }
    }
    __syncthreads();

    const int w = d >> 6, lane = d & 63;
    for (int i = w; i < 31; i += 8) {
        int n = nid[i];
        float v[8]; float s1 = 0.f, s2 = 0.f;
        #pragma unroll
        for (int k = 0; k < 8; k++) {
            v[k] = Y[i][lane + 64 * k];
            s1 += v[k]; s2 += v[k] * v[k];
        }
        #pragma unroll
        for (int off = 32; off > 0; off >>= 1) {
            s1 += __shfl_xor(s1, off);
            s2 += __shfl_xor(s2, off);
        }
        float mu = s1 * (1.f / 512.f);
        float inv = rsqrtf(s2 * (1.f / 512.f) - mu * mu + 1e-5f);
        #pragma unroll
        for (int k = 0; k < 8; k++) {
            int ch = lane + 64 * k;
            out[(size_t)n * 512 + ch] = (v[k] - mu) * inv * gamma[ch] + beta[ch];
        }
    }
}

extern "C" void kernel_launch(void* const* d_in, const int* in_sizes, int n_in,
                              void* d_out, int out_size, void* d_ws, size_t ws_size,
                              hipStream_t stream) {
    const float* s_in   = (const float*)d_in[0];
    const float* w      = (const float*)d_in[1];
    const float* W_in    = (const float*)d_in[4];
    const float* b_in    = (const float*)d_in[5];
    const float* W_delta = (const float*)d_in[6];
    const float* b_delta = (const float*)d_in[7];
    const float* W_w     = (const float*)d_in[8];
    const float* b_w     = (const float*)d_in[9];
    const float* A_log   = (const float*)d_in[10];
    const float* Dv      = (const float*)d_in[11];
    const float* W_B     = (const float*)d_in[12];
    const float* b_B     = (const float*)d_in[13];
    const float* W_C     = (const float*)d_in[14];
    const float* b_C     = (const float*)d_in[15];
    const float* gamma   = (const float*)d_in[16];
    const float* beta    = (const float*)d_in[17];
    float* out = (float*)d_out;

    const int Nn = in_sizes[1];           // 16383

    float* ws    = (float*)d_ws;
    float* lw    = ws;                                      // 16384
    float* delta = lw + MPAD;                               // 16384*512 fp32
    float* Bm    = delta + (size_t)MPAD * 512;              // 16384*16
    float* Cm    = Bm + (size_t)MPAD * 16;                  // 16384*16
    float* H9    = Cm + (size_t)MPAD * 16;                  // 512*512*16
    unsigned short* s_bf  = (unsigned short*)(H9 + (size_t)N_CKPT * 512 * 16);  // 16384*512
    unsigned short* x_bf  = s_bf + (size_t)MPAD * 512;      // 16384*512
    unsigned short* Win_bf = x_bf + (size_t)MPAD * 512;     // 512*512
    unsigned short* Wd_bf  = Win_bf + 512 * 512;            // 512*512
    unsigned short* Wbc_bf = Wd_bf + 512 * 512;             // 32*512

    prep_kernel<<<MPAD + 1024 + 32, 256, 0, stream>>>(s_in, w, W_in, W_delta, W_B, W_C,
                                                      s_bf, lw, Win_bf, Wd_bf, Wbc_bf, Nn);

    dim3 gg(4, 128);
    gemm_mfma<<<gg, 256, 0, stream>>>(s_bf, Win_bf, nullptr, x_bf,
                                      b_in, lw, W_in + 512, 513, nullptr, 0);
    gemm_mfma<<<gg, 256, 0, stream>>>(x_bf, Wd_bf, delta, nullptr,
                                      b_delta, lw, W_w, 1, b_w, 1);

    bc_gemm<<<128, 256, 0, stream>>>(x_bf, Wbc_bf, b_B, b_C, Bm, Cm);

    ckpt_kernel<<<N_CKPT, 256, 0, stream>>>(x_bf, delta, Bm, A_log, H9);

    scan_shallow<<<CKPT_BASE, 256, 0, stream>>>(x_bf, delta, Bm, Cm, A_log, Dv,
                                                gamma, beta, out);

    scan_deep<<<N_CKPT, 512, 0, stream>>>(x_bf, delta, Bm, Cm, H9, A_log, Dv,
                                          gamma, beta, out);
}

// Round 6
// 263.048 us; speedup vs baseline: 2.6705x; 1.0524x over previous
//
#include <hip/hip_runtime.h>
#include <hip/hip_bf16.h>
#include <math.h>

#define D_SSM 512
#define D_STATE 16
#define CKPT_BASE 511     // first index of level 9
#define CKPT_END 1023     // first index of level 10
#define N_CKPT 512        // nodes at level 9
#define MPAD 16384

typedef __attribute__((ext_vector_type(8))) short short8;
typedef __attribute__((ext_vector_type(4))) float floatx4;

__device__ __forceinline__ unsigned short f2bf(float f) {
    unsigned int u = __float_as_uint(f);
    unsigned int r = (u + 0x7fffu + ((u >> 16) & 1u)) >> 16;
    return (unsigned short)r;
}
__device__ __forceinline__ float bf2f(unsigned short u) {
    return __uint_as_float(((unsigned int)u) << 16);
}
__device__ __forceinline__ void g2lds16(const void* g, void* l) {
    __builtin_amdgcn_global_load_lds(
        (const __attribute__((address_space(1))) void*)g,
        (__attribute__((address_space(3))) void*)l, 16, 0, 0);
}

// ---------------- prep: cast s/W_in/W_delta/W_B/W_C to bf16, compute lw ----------------
__global__ __launch_bounds__(256) void prep_kernel(
    const float* __restrict__ s, const float* __restrict__ w,
    const float* __restrict__ W_in, const float* __restrict__ W_delta,
    const float* __restrict__ W_B, const float* __restrict__ W_C,
    unsigned short* __restrict__ s_bf, float* __restrict__ lw,
    unsigned short* __restrict__ Win_bf, unsigned short* __restrict__ Wd_bf,
    unsigned short* __restrict__ Wbc_bf, int Nn)
{
    const int b = blockIdx.x, t = threadIdx.x;
    if (b < MPAD) {
        unsigned int pack = 0;
        if (b < Nn) {
            float2 sv = *(const float2*)(s + (size_t)b * 512 + t * 2);
            pack = (unsigned int)f2bf(sv.x) | ((unsigned int)f2bf(sv.y) << 16);
        }
        *(unsigned int*)(s_bf + (size_t)b * 512 + t * 2) = pack;
        if (t == 0) lw[b] = (b < Nn) ? logf(w[b] + 1e-6f) : 0.f;
    } else if (b < MPAD + 512) {
        int c = b - MPAD;
        float a0 = W_in[(size_t)c * 513 + t * 2];
        float a1 = W_in[(size_t)c * 513 + t * 2 + 1];
        *(unsigned int*)(Win_bf + (size_t)c * 512 + t * 2) =
            (unsigned int)f2bf(a0) | ((unsigned int)f2bf(a1) << 16);
    } else if (b < MPAD + 1024) {
        int c = b - MPAD - 512;
        float2 wv = *(const float2*)(W_delta + (size_t)c * 512 + t * 2);
        *(unsigned int*)(Wd_bf + (size_t)c * 512 + t * 2) =
            (unsigned int)f2bf(wv.x) | ((unsigned int)f2bf(wv.y) << 16);
    } else {
        int c = b - MPAD - 1024;   // 0..31: rows 0..15 = W_B, 16..31 = W_C
        const float* src = (c < 16) ? (W_B + (size_t)c * 512) : (W_C + (size_t)(c - 16) * 512);
        float2 wv = *(const float2*)(src + t * 2);
        *(unsigned int*)(Wbc_bf + (size_t)c * 512 + t * 2) =
            (unsigned int)f2bf(wv.x) | ((unsigned int)f2bf(wv.y) << 16);
    }
}

// ---------------- bf16 MFMA GEMM, 64x128 tile, double-buffered LDS ----------------
// mode 0: o = z + bias[c] + lw[r]*wcol[c*wcol_stride]; store bf16 -> outbf
// mode 1: o = softplus(z+bias[c]) * sigmoid(lw[r]*wcol[c]+bw[c]); store fp32 -> outf
__global__ __launch_bounds__(256) void gemm_mfma(
    const unsigned short* __restrict__ Abf,   // [16384][512] bf16
    const unsigned short* __restrict__ Wbf,   // [512][512] bf16
    float* __restrict__ outf,
    unsigned short* __restrict__ outbf,
    const float* __restrict__ bias,
    const float* __restrict__ lw,
    const float* __restrict__ wcol, int wcol_stride,
    const float* __restrict__ bw,
    int mode)
{
    __shared__ __align__(16) short As[2][64 * 32];    // 4 KB per buffer
    __shared__ __align__(16) short Bs[2][128 * 32];   // 8 KB per buffer
    const int tid = threadIdx.x;
    const int wave = tid >> 6, lane = tid & 63;
    const int row0 = blockIdx.y * 64;
    const int col0 = blockIdx.x * 128;
    const int wr = (wave >> 1) * 32;     // wave's 32-row strip
    const int wc = (wave & 1) * 64;      // wave's 64-col strip

    floatx4 acc[2][4] = {};

    const int srow = lane >> 2;                       // 0..15
    const int sg   = (lane & 3) ^ ((srow >> 1) & 3);  // XOR swizzle
    const int scol = sg * 8;

    // per-thread staging: 1 A-chunk (16 rows), 2 B-chunks
    const unsigned short* Ag = Abf + (size_t)(row0 + wave * 16 + srow) * 512 + scol;
    const unsigned short* Wg0 = Wbf + (size_t)(col0 + (wave * 2 + 0) * 16 + srow) * 512 + scol;
    const unsigned short* Wg1 = Wbf + (size_t)(col0 + (wave * 2 + 1) * 16 + srow) * 512 + scol;

    {   // stage k-chunk 0 into buffer 0
        g2lds16(Ag, (char*)&As[0][0] + wave * 1024);
        g2lds16(Wg0, (char*)&Bs[0][0] + (wave * 2 + 0) * 1024);
        g2lds16(Wg1, (char*)&Bs[0][0] + (wave * 2 + 1) * 1024);
    }
    __syncthreads();

    for (int it = 0; it < 16; it++) {
        const int cur = it & 1;
        if (it < 15) {   // prefetch next chunk into the other buffer (DMA overlaps compute)
            int k1 = (it + 1) * 32;
            g2lds16(Ag + k1, (char*)&As[cur ^ 1][0] + wave * 1024);
            g2lds16(Wg0 + k1, (char*)&Bs[cur ^ 1][0] + (wave * 2 + 0) * 1024);
            g2lds16(Wg1 + k1, (char*)&Bs[cur ^ 1][0] + (wave * 2 + 1) * 1024);
        }

        short8 af[2], bfr[4];
        #pragma unroll
        for (int i = 0; i < 2; i++) {
            int m = wr + i * 16 + (lane & 15);
            int gm = (lane >> 4) ^ ((m >> 1) & 3);
            af[i] = *(const short8*)&As[cur][m * 32 + gm * 8];
        }
        #pragma unroll
        for (int j = 0; j < 4; j++) {
            int n = wc + j * 16 + (lane & 15);
            int gn = (lane >> 4) ^ ((n >> 1) & 3);
            bfr[j] = *(const short8*)&Bs[cur][n * 32 + gn * 8];
        }
        #pragma unroll
        for (int i = 0; i < 2; i++)
            #pragma unroll
            for (int j = 0; j < 4; j++)
                acc[i][j] = __builtin_amdgcn_mfma_f32_16x16x32_bf16(af[i], bfr[j], acc[i][j], 0, 0, 0);
        __syncthreads();   // drains prefetch vmcnt + guards buffer reuse
    }

    // epilogue: C/D layout col=lane&15, row=(lane>>4)*4+reg
    #pragma unroll
    for (int i = 0; i < 2; i++) {
        #pragma unroll
        for (int reg = 0; reg < 4; reg++) {
            int r = row0 + wr + i * 16 + (lane >> 4) * 4 + reg;
            float lwr = lw[r];
            #pragma unroll
            for (int j = 0; j < 4; j++) {
                int c = col0 + wc + j * 16 + (lane & 15);
                float z = acc[i][j][reg] + bias[c];
                if (mode == 0) {
                    float o = z + lwr * wcol[(size_t)c * wcol_stride];
                    outbf[(size_t)r * 512 + c] = f2bf(o);
                } else {
                    float sp = (z > 15.f) ? z : log1pf(__expf(z));
                    float sg2 = 1.f / (1.f + __expf(-(lwr * wcol[c] + bw[c])));
                    outf[(size_t)r * 512 + c] = sp * sg2;
                }
            }
        }
    }
}

// ---------------- B/C via skinny MFMA GEMM: [16384x512] @ [512x32] ----------------
__global__ __launch_bounds__(256) void bc_gemm(
    const unsigned short* __restrict__ Abf,    // x_bf [16384][512]
    const unsigned short* __restrict__ Wbc,    // [32][512] bf16
    const float* __restrict__ b_B, const float* __restrict__ b_C,
    float* __restrict__ Bm, float* __restrict__ Cm)
{
    __shared__ __align__(16) short As[128 * 32];
    __shared__ __align__(16) short Ws[32 * 512];
    const int tid = threadIdx.x;
    const int wave = tid >> 6, lane = tid & 63;
    const int row0 = blockIdx.x * 128;
    const int wr = wave * 32;

    for (int i = 0; i < 8; i++) {
        int fg = i * 256 + tid;          // flat k-group id, 0..2047
        int n = fg >> 6, kgg = fg & 63;
        short8 v = *(const short8*)(Wbc + (size_t)n * 512 + kgg * 8);
        *(short8*)&Ws[n * 512 + ((kgg ^ (n & 7)) * 8)] = v;
    }

    floatx4 acc[2][2] = {};

    const int srow = lane >> 2;
    const int sgz  = (lane & 3) ^ ((srow >> 1) & 3);
    const int scol = sgz * 8;

    for (int k0 = 0; k0 < 512; k0 += 32) {
        #pragma unroll
        for (int j = 0; j < 2; j++) {
            int c = wave * 2 + j;
            int r = c * 16 + srow;
            g2lds16(Abf + (size_t)(row0 + r) * 512 + k0 + scol, (char*)As + c * 1024);
        }
        __syncthreads();

        short8 af[2], bfr[2];
        #pragma unroll
        for (int i = 0; i < 2; i++) {
            int m = wr + i * 16 + (lane & 15);
            int gm = (lane >> 4) ^ ((m >> 1) & 3);
            af[i] = *(const short8*)&As[m * 32 + gm * 8];
        }
        #pragma unroll
        for (int j = 0; j < 2; j++) {
            int n = j * 16 + (lane & 15);
            int Gg = (k0 >> 3) + (lane >> 4);
            bfr[j] = *(const short8*)&Ws[n * 512 + ((Gg ^ (n & 7)) * 8)];
        }
        #pragma unroll
        for (int i = 0; i < 2; i++)
            #pragma unroll
            for (int j = 0; j < 2; j++)
                acc[i][j] = __builtin_amdgcn_mfma_f32_16x16x32_bf16(af[i], bfr[j], acc[i][j], 0, 0, 0);
        __syncthreads();
    }

    const int s = lane & 15;
    #pragma unroll
    for (int i = 0; i < 2; i++) {
        #pragma unroll
        for (int reg = 0; reg < 4; reg++) {
            int r = row0 + wr + i * 16 + (lane >> 4) * 4 + reg;
            Bm[(size_t)r * 16 + s] = acc[i][0][reg] + b_B[s];
            Cm[(size_t)r * 16 + s] = acc[i][1][reg] + b_C[s];
        }
    }
}

// fast path valid when As[s] == (s+1)*As[0]
__device__ __forceinline__ bool geo_check(const float* As) {
    bool ok = true;
    #pragma unroll
    for (int s = 1; s < 16; s++) {
        float want = (float)(s + 1) * As[0];
        ok = ok && (fabsf(As[s] - want) <= 1e-4f * (float)(s + 1));
    }
    return ok;
}

// ---------------- checkpoint kernel: H for all level-9 nodes ----------------
__global__ __launch_bounds__(256) void ckpt_kernel(
    const unsigned short* __restrict__ x_bf, const float* __restrict__ delta,
    const float* __restrict__ Bm, const float* __restrict__ A_log,
    float* __restrict__ H9)
{
    const int n9 = blockIdx.x;
    const int t = threadIdx.x;
    const int d0 = t, d1 = t + 256;

    float As0[16], As1[16], acc0[16], acc1[16];
    #pragma unroll
    for (int s = 0; s < 16; s++) {
        As0[s] = -__expf(A_log[d0 * 16 + s]);
        As1[s] = -__expf(A_log[d1 * 16 + s]);
        acc0[s] = 0.f; acc1[s] = 0.f;
    }
    const bool fast = geo_check(As0) && geo_check(As1);

    float cum0 = 0.f, cum1 = 0.f;
    int a = CKPT_BASE + n9;
    while (a >= 0) {
        float da0 = delta[(size_t)a * 512 + d0];
        float da1 = delta[(size_t)a * 512 + d1];
        float bx0 = da0 * bf2f(x_bf[(size_t)a * 512 + d0]);
        float bx1 = da1 * bf2f(x_bf[(size_t)a * 512 + d1]);
        if (fast) {
            float r0 = __expf(As0[0] * cum0);
            float r1 = __expf(As1[0] * cum1);
            float pw0 = r0, pw1 = r1;
            #pragma unroll
            for (int s = 0; s < 16; s++) {
                float Bs = Bm[a * 16 + s];
                acc0[s] = fmaf(bx0 * pw0, Bs, acc0[s]);
                acc1[s] = fmaf(bx1 * pw1, Bs, acc1[s]);
                pw0 *= r0; pw1 *= r1;
            }
        } else {
            #pragma unroll
            for (int s = 0; s < 16; s++) {
                float Bs = Bm[a * 16 + s];
                acc0[s] = fmaf(bx0 * __expf(As0[s] * cum0), Bs, acc0[s]);
                acc1[s] = fmaf(bx1 * __expf(As1[s] * cum1), Bs, acc1[s]);
            }
        }
        cum0 += da0; cum1 += da1;
        a = (a - 1) >> 1;
    }

    float* p0 = H9 + ((size_t)n9 * 512 + d0) * 16;
    float* p1 = H9 + ((size_t)n9 * 512 + d1) * 16;
    #pragma unroll
    for (int s = 0; s < 16; s++) { p0[s] = acc0[s]; p1[s] = acc1[s]; }
}

// ---------------- shallow scan (nodes 0..510, levels 0..8): walk + LN ----------------
__global__ __launch_bounds__(256) void scan_shallow(
    const unsigned short* __restrict__ x_bf, const float* __restrict__ delta,
    const float* __restrict__ Bm, const float* __restrict__ Cm,
    const float* __restrict__ A_log, const float* __restrict__ Dv,
    const float* __restrict__ gamma, const float* __restrict__ beta,
    float* __restrict__ out)
{
    const int n = blockIdx.x;
    const int t = threadIdx.x;
    const int d0 = t, d1 = t + 256;

    float As0[16], As1[16], acc0[16], acc1[16];
    #pragma unroll
    for (int s = 0; s < 16; s++) {
        As0[s] = -__expf(A_log[d0 * 16 + s]);
        As1[s] = -__expf(A_log[d1 * 16 + s]);
        acc0[s] = 0.f; acc1[s] = 0.f;
    }
    const bool fast = geo_check(As0) && geo_check(As1);

    float cum0 = 0.f, cum1 = 0.f;
    int a = n;
    while (a >= 0) {
        float da0 = delta[(size_t)a * 512 + d0];
        float da1 = delta[(size_t)a * 512 + d1];
        float bx0 = da0 * bf2f(x_bf[(size_t)a * 512 + d0]);
        float bx1 = da1 * bf2f(x_bf[(size_t)a * 512 + d1]);
        if (fast) {
            float r0 = __expf(As0[0] * cum0);
            float r1 = __expf(As1[0] * cum1);
            float pw0 = r0, pw1 = r1;
            #pragma unroll
            for (int s = 0; s < 16; s++) {
                float Bs = Bm[a * 16 + s];
                acc0[s] = fmaf(bx0 * pw0, Bs, acc0[s]);
                acc1[s] = fmaf(bx1 * pw1, Bs, acc1[s]);
                pw0 *= r0; pw1 *= r1;
            }
        } else {
            #pragma unroll
            for (int s = 0; s < 16; s++) {
                float Bs = Bm[a * 16 + s];
                acc0[s] = fmaf(bx0 * __expf(As0[s] * cum0), Bs, acc0[s]);
                acc1[s] = fmaf(bx1 * __expf(As1[s] * cum1), Bs, acc1[s]);
            }
        }
        cum0 += da0; cum1 += da1;
        a = (a - 1) >> 1;
    }

    float xn0 = bf2f(x_bf[(size_t)n * 512 + d0]);
    float xn1 = bf2f(x_bf[(size_t)n * 512 + d1]);
    float y0 = Dv[d0] * xn0, y1 = Dv[d1] * xn1;
    #pragma unroll
    for (int s = 0; s < 16; s++) {
        float Cs = Cm[(size_t)n * 16 + s];
        y0 += Cs * acc0[s];
        y1 += Cs * acc1[s];
    }

    float s1 = y0 + y1;
    float s2 = y0 * y0 + y1 * y1;
    #pragma unroll
    for (int off = 32; off > 0; off >>= 1) {
        s1 += __shfl_xor(s1, off);
        s2 += __shfl_xor(s2, off);
    }
    __shared__ float red[8];
    int wid = t >> 6, lane = t & 63;
    if (lane == 0) { red[wid] = s1; red[wid + 4] = s2; }
    __syncthreads();
    float S1 = red[0] + red[1] + red[2] + red[3];
    float S2 = red[4] + red[5] + red[6] + red[7];
    float mu = S1 * (1.f / 512.f);
    float var = S2 * (1.f / 512.f) - mu * mu;
    float inv = rsqrtf(var + 1e-5f);
    out[(size_t)n * 512 + d0] = (y0 - mu) * inv * gamma[d0] + beta[d0];
    out[(size_t)n * 512 + d1] = (y1 - mu) * inv * gamma[d1] + beta[d1];
}

// ---------------- deep scan: one block per level-9 subtree, DFS forward sweep ----------------
__global__ __launch_bounds__(512) void scan_deep(
    const unsigned short* __restrict__ x_bf, const float* __restrict__ delta,
    const float* __restrict__ Bm, const float* __restrict__ Cm,
    const float* __restrict__ H9,
    const float* __restrict__ A_log, const float* __restrict__ Dv,
    const float* __restrict__ gamma, const float* __restrict__ beta,
    float* __restrict__ out)
{
    __shared__ float Y[31][512];
    __shared__ int nid[31];
    const int p = blockIdx.x;
    const int d = threadIdx.x;
    const int a9 = CKPT_BASE + p;

    float As0 = -__expf(A_log[d * 16]);
    bool fast = true;
    #pragma unroll
    for (int s = 1; s < 16; s++) {
        float As = -__expf(A_log[d * 16 + s]);
        fast = fast && (fabsf(As - (float)(s + 1) * As0) <= 1e-4f * (float)(s + 1));
    }

    float H9v[16];
    #pragma unroll
    for (int s = 0; s < 16; s++) H9v[s] = H9[((size_t)p * 512 + d) * 16 + s];

    {
        float xv = bf2f(x_bf[(size_t)a9 * 512 + d]);
        float y = Dv[d] * xv;
        #pragma unroll
        for (int s = 0; s < 16; s++) y = fmaf(Cm[(size_t)a9 * 16 + s], H9v[s], y);
        Y[0][d] = y;
        if (d == 0) nid[0] = a9;
    }

    auto step = [&](int n, const float* Hp, float* Hc, int slot) {
        float dlt = delta[(size_t)n * 512 + d];
        float xv = bf2f(x_bf[(size_t)n * 512 + d]);
        float bx = dlt * xv;
        const float* Bn = Bm + (size_t)n * 16;
        const float* Cn = Cm + (size_t)n * 16;
        float y = Dv[d] * xv;
        if (fast) {
            float r = __expf(As0 * dlt);
            float pw = r;
            #pragma unroll
            for (int s = 0; s < 16; s++) {
                Hc[s] = fmaf(pw, Hp[s], bx * Bn[s]);
                y = fmaf(Cn[s], Hc[s], y);
                pw *= r;
            }
        } else {
            #pragma unroll
            for (int s = 0; s < 16; s++) {
                float Ab = __expf(dlt * (-__expf(A_log[d * 16 + s])));
                Hc[s] = fmaf(Ab, Hp[s], bx * Bn[s]);
                y = fmaf(Cn[s], Hc[s], y);
            }
        }
        Y[slot][d] = y;
        if (d == 0) nid[slot] = n;
    };

    float H10[16], H11[16], H12[16], H13[16];
    int slot = 1;
    #pragma unroll
    for (int c0 = 0; c0 < 2; c0++) {
        int n10 = 2 * a9 + 1 + c0;
        step(n10, H9v, H10, slot++);
        #pragma unroll
        for (int c1 = 0; c1 < 2; c1++) {
            int n11 = 2 * n10 + 1 + c1;
            step(n11, H10, H11, slot++);
            #pragma unroll
            for (int c2 = 0; c2 < 2; c2++) {
                int n12 = 2 * n11 + 1 + c2;
                step(n12, H11, H12, slot++);
                #pragma unroll
                for (int c3 = 0; c3 < 2; c3++) {
                    int n13 = 2 * n12 + 1 + c3;
                    step(n13, H12, H13, slot++);
                }
            }
        }
    }
    __syncthreads();

    const int w = d >> 6, lane = d & 63;
    for (int i = w; i < 31; i += 8) {
        int n = nid[i];
        float v[8]; float s1 = 0.f, s2 = 0.f;
        #pragma unroll
        for (int k = 0; k < 8; k++) {
            v[k] = Y[i][lane + 64 * k];
            s1 += v[k]; s2 += v[k] * v[k];
        }
        #pragma unroll
        for (int off = 32; off > 0; off >>= 1) {
            s1 += __shfl_xor(s1, off);
            s2 += __shfl_xor(s2, off);
        }
        float mu = s1 * (1.f / 512.f);
        float inv = rsqrtf(s2 * (1.f / 512.f) - mu * mu + 1e-5f);
        #pragma unroll
        for (int k = 0; k < 8; k++) {
            int ch = lane + 64 * k;
            out[(size_t)n * 512 + ch] = (v[k] - mu) * inv * gamma[ch] + beta[ch];
        }
    }
}

extern "C" void kernel_launch(void* const* d_in, const int* in_sizes, int n_in,
                              void* d_out, int out_size, void* d_ws, size_t ws_size,
                              hipStream_t stream) {
    const float* s_in   = (const float*)d_in[0];
    const float* w      = (const float*)d_in[1];
    const float* W_in    = (const float*)d_in[4];
    const float* b_in    = (const float*)d_in[5];
    const float* W_delta = (const float*)d_in[6];
    const float* b_delta = (const float*)d_in[7];
    const float* W_w     = (const float*)d_in[8];
    const float* b_w     = (const float*)d_in[9];
    const float* A_log   = (const float*)d_in[10];
    const float* Dv      = (const float*)d_in[11];
    const float* W_B     = (const float*)d_in[12];
    const float* b_B     = (const float*)d_in[13];
    const float* W_C     = (const float*)d_in[14];
    const float* b_C     = (const float*)d_in[15];
    const float* gamma   = (const float*)d_in[16];
    const float* beta    = (const float*)d_in[17];
    float* out = (float*)d_out;

    const int Nn = in_sizes[1];           // 16383

    float* ws    = (float*)d_ws;
    float* lw    = ws;                                      // 16384
    float* delta = lw + MPAD;                               // 16384*512 fp32
    float* Bm    = delta + (size_t)MPAD * 512;              // 16384*16
    float* Cm    = Bm + (size_t)MPAD * 16;                  // 16384*16
    float* H9    = Cm + (size_t)MPAD * 16;                  // 512*512*16
    unsigned short* s_bf  = (unsigned short*)(H9 + (size_t)N_CKPT * 512 * 16);  // 16384*512
    unsigned short* x_bf  = s_bf + (size_t)MPAD * 512;      // 16384*512
    unsigned short* Win_bf = x_bf + (size_t)MPAD * 512;     // 512*512
    unsigned short* Wd_bf  = Win_bf + 512 * 512;            // 512*512
    unsigned short* Wbc_bf = Wd_bf + 512 * 512;             // 32*512

    prep_kernel<<<MPAD + 1024 + 32, 256, 0, stream>>>(s_in, w, W_in, W_delta, W_B, W_C,
                                                      s_bf, lw, Win_bf, Wd_bf, Wbc_bf, Nn);

    dim3 gg(4, 256);   // 128-col x 64-row tiles -> 1024 blocks (4/CU)
    gemm_mfma<<<gg, 256, 0, stream>>>(s_bf, Win_bf, nullptr, x_bf,
                                      b_in, lw, W_in + 512, 513, nullptr, 0);
    gemm_mfma<<<gg, 256, 0, stream>>>(x_bf, Wd_bf, delta, nullptr,
                                      b_delta, lw, W_w, 1, b_w, 1);

    bc_gemm<<<128, 256, 0, stream>>>(x_bf, Wbc_bf, b_B, b_C, Bm, Cm);

    ckpt_kernel<<<N_CKPT, 256, 0, stream>>>(x_bf, delta, Bm, A_log, H9);

    scan_shallow<<<CKPT_BASE, 256, 0, stream>>>(x_bf, delta, Bm, Cm, A_log, Dv,
                                                gamma, beta, out);

    scan_deep<<<N_CKPT, 512, 0, stream>>>(x_bf, delta, Bm, Cm, H9, A_log, Dv,
                                          gamma, beta, out);
}